// Round 8
// baseline (419.203 us; speedup 1.0000x reference)
//
#include <hip/hip_runtime.h>
#include <cstdint>

// Problem constants
#define Bq   2
#define Tq   2048
#define Dq   2048
#define Hq   16
#define DKq  64
#define DVq  128
#define Cq   64          // chunk len
#define NCq  32          // chunks
#define Mq   4096        // B*T
#define NBH  32          // B*H

typedef _Float16 f16;
typedef f16 f16x4 __attribute__((ext_vector_type(4)));
typedef f16 f16x8 __attribute__((ext_vector_type(8)));
typedef float f32x4 __attribute__((ext_vector_type(4)));
typedef unsigned short u16;
typedef u16 u16x8 __attribute__((ext_vector_type(8)));

__device__ __forceinline__ void gl_lds16(const void* g, void* l) {
    __builtin_amdgcn_global_load_lds(
        (const __attribute__((address_space(1))) uint32_t*)g,
        (__attribute__((address_space(3))) uint32_t*)l, 16, 0, 0);
}

#define BARX()   asm volatile("s_barrier" ::: "memory")
#define LGKM0()  asm volatile("s_waitcnt lgkmcnt(0)" ::: "memory")
#define VMW8()   asm volatile("s_waitcnt vmcnt(8)" ::: "memory")
#define VMW6()   asm volatile("s_waitcnt vmcnt(6)" ::: "memory")

// ---------------- prep1: weight transpose + hs f16 convert + low-rank t_gk/t_g ----------------
// blk [0,12288): transpose Wq/Wk/Wv/Wo -> Qkv/WoT (f16)
// blk [12288,16384): hs f32 -> f16
// blk [16384,16640): t_gk = hs@Wgk1, t_g = hs@Wg1 (f32)
__global__ __launch_bounds__(256) void prep1(const float* __restrict__ Wq,
                                             const float* __restrict__ Wk,
                                             const float* __restrict__ Wv,
                                             const float* __restrict__ Wo,
                                             const float* __restrict__ hs,
                                             const float* __restrict__ Wgk1,
                                             const float* __restrict__ Wg1,
                                             f16* __restrict__ Qkv, f16* __restrict__ WoT,
                                             f16* __restrict__ Xh,
                                             float* __restrict__ t_gk,
                                             float* __restrict__ t_g) {
    __shared__ __align__(16) char smem_raw[65536];
    int blk = blockIdx.x;
    int tid = threadIdx.x;
    if (blk < 12288) {
        float* sh = (float*)smem_raw;    // 16 KB
        const float* W; f16* Dh; int N, nt, kt; long rowoff;
        if (blk < 2048)      { W = Wq; N = 1024; int t = blk;        nt = t & 31; kt = t >> 5; Dh = Qkv; rowoff = 0; }
        else if (blk < 4096) { W = Wk; N = 1024; int t = blk - 2048; nt = t & 31; kt = t >> 5; Dh = Qkv; rowoff = 1024; }
        else if (blk < 8192) { W = Wv; N = 2048; int t = blk - 4096; nt = t & 63; kt = t >> 6; Dh = Qkv; rowoff = 2048; }
        else                 { W = Wo; N = 2048; int t = blk - 8192; nt = t & 63; kt = t >> 6; Dh = WoT; rowoff = 0; }
        int tx = tid & 31, ty = tid >> 5;   // 32 x 8
#pragma unroll
        for (int i = 0; i < 4; i++) {
            int k = kt * 32 + ty + i * 8;
            int n = nt * 32 + tx;
            sh[tx * 33 + ty + i * 8] = W[(long)k * N + n];
        }
        __syncthreads();
#pragma unroll
        for (int i = 0; i < 4; i++) {
            int n = nt * 32 + ty + i * 8;
            int k = kt * 32 + tx;
            Dh[(rowoff + n) * 2048L + k] = (f16)sh[(ty + i * 8) * 33 + tx];
        }
    } else if (blk < 16384) {
        long i = ((long)(blk - 12288) * 256 + tid) * 8;
        float4 a = *(const float4*)(hs + i);
        float4 b = *(const float4*)(hs + i + 4);
        f16x8 h;
        h[0] = (f16)a.x; h[1] = (f16)a.y; h[2] = (f16)a.z; h[3] = (f16)a.w;
        h[4] = (f16)b.x; h[5] = (f16)b.y; h[6] = (f16)b.z; h[7] = (f16)b.w;
        *(f16x8*)(Xh + i) = h;
    } else {
        float* sW = (float*)smem_raw;    // 64 KB, granule-swizzled
        int bq = blk - 16384;
        int r = tid >> 4, seg = tid & 15;
        long row = (long)bq * 16 + r;
        float acc[32];
#pragma unroll
        for (int c = 0; c < 32; c++) acc[c] = 0.f;
        for (int kc = 0; kc < 2048; kc += 512) {
            __syncthreads();
#pragma unroll
            for (int i = 0; i < 16; i++) {
                int s = tid + i * 256;
                int k = s >> 3, q = s & 7;
                float4 w = (q < 4) ? *(const float4*)(Wgk1 + (long)(kc + k) * 16 + q * 4)
                                   : *(const float4*)(Wg1  + (long)(kc + k) * 16 + (q - 4) * 4);
                int qs = q ^ ((k >> 5) & 7);
                *(float4*)&sW[k * 32 + qs * 4] = w;
            }
            __syncthreads();
            const float* hp = hs + row * 2048 + kc + seg * 32;
            int xr = seg & 7;
#pragma unroll
            for (int k4 = 0; k4 < 8; k4++) {
                float4 hv = *(const float4*)(hp + k4 * 4);
                float hvv[4] = {hv.x, hv.y, hv.z, hv.w};
#pragma unroll
                for (int u = 0; u < 4; u++) {
                    int k = seg * 32 + k4 * 4 + u;
                    const float* wr = &sW[k * 32];
#pragma unroll
                    for (int q = 0; q < 8; q++) {
                        float4 wv = *(const float4*)(wr + ((q ^ xr) * 4));
                        acc[q * 4 + 0] += hvv[u] * wv.x;
                        acc[q * 4 + 1] += hvv[u] * wv.y;
                        acc[q * 4 + 2] += hvv[u] * wv.z;
                        acc[q * 4 + 3] += hvv[u] * wv.w;
                    }
                }
            }
        }
#pragma unroll
        for (int c = 0; c < 32; c++) {
            acc[c] += __shfl_xor(acc[c], 1);
            acc[c] += __shfl_xor(acc[c], 2);
            acc[c] += __shfl_xor(acc[c], 4);
            acc[c] += __shfl_xor(acc[c], 8);
        }
        if (seg == 0) {
            float4 a;
            a.x = acc[0];  a.y = acc[1];  a.z = acc[2];  a.w = acc[3];  *(float4*)(t_gk + row * 16)     = a;
            a.x = acc[4];  a.y = acc[5];  a.z = acc[6];  a.w = acc[7];  *(float4*)(t_gk + row * 16 + 4) = a;
            a.x = acc[8];  a.y = acc[9];  a.z = acc[10]; a.w = acc[11]; *(float4*)(t_gk + row * 16 + 8) = a;
            a.x = acc[12]; a.y = acc[13]; a.z = acc[14]; a.w = acc[15]; *(float4*)(t_gk + row * 16 + 12)= a;
            a.x = acc[16]; a.y = acc[17]; a.z = acc[18]; a.w = acc[19]; *(float4*)(t_g + row * 16)      = a;
            a.x = acc[20]; a.y = acc[21]; a.z = acc[22]; a.w = acc[23]; *(float4*)(t_g + row * 16 + 4)  = a;
            a.x = acc[24]; a.y = acc[25]; a.z = acc[26]; a.w = acc[27]; *(float4*)(t_g + row * 16 + 8)  = a;
            a.x = acc[28]; a.y = acc[29]; a.z = acc[30]; a.w = acc[31]; *(float4*)(t_g + row * 16 + 12) = a;
        }
    }
}

// ---------------- 256x256 8-phase f16 GEMM (qkv) ----------------
// Staging split: STG_B at phase 3 (B-halves of this buf dead after phase-2 barrier),
// STG_A at phase 4. VMW8 semantics unchanged (8 newest outstanding = ph3+ph4 stages).
__global__ __launch_bounds__(512, 2) void gemm256q(const f16* __restrict__ A,
                                                   const f16* __restrict__ Bt,
                                                   f16* __restrict__ h0,
                                                   f16* __restrict__ h1,
                                                   f16* __restrict__ h2) {
    __shared__ __align__(16) f16 sA[2][16384];
    __shared__ __align__(16) f16 sB[2][16384];
    int tid = threadIdx.x;
    int wave = tid >> 6, lane = tid & 63;
    int quad = lane >> 4, l16 = lane & 15;
    int wm = wave >> 2, wn = wave & 3;

    int cpx = (int)gridDim.x >> 3;
    int wid = ((int)blockIdx.x & 7) * cpx + ((int)blockIdx.x >> 3);
    int bm = wid & 15, bn = wid >> 4;

    const f16* Ab = A  + (long)bm * 256 * 2048;
    const f16* Bb = Bt + (long)bn * 256 * 2048;

    int srow = tid >> 3;
    int gsrc = ((tid & 7) ^ (srow & 7)) * 8;
    const f16* Asrc = Ab + (long)srow * 2048 + gsrc;
    const f16* Bsrc = Bb + (long)srow * 2048 + gsrc;

#define STG_A(P, KT) do { \
    _Pragma("unroll") \
    for (int q_ = 0; q_ < 4; q_++) \
        gl_lds16(Asrc + (KT) * 64 + (long)q_ * 64 * 2048, &sA[P][tid * 8] + q_ * 4096); \
} while (0)
#define STG_B(P, KT) do { \
    _Pragma("unroll") \
    for (int q_ = 0; q_ < 4; q_++) \
        gl_lds16(Bsrc + (KT) * 64 + (long)q_ * 64 * 2048, &sB[P][tid * 8] + q_ * 4096); \
} while (0)

    int go0 = (quad ^ (l16 & 7)) * 8;
    int go1 = go0 ^ 32;
    const f16* aB0 = &sA[0][(wm * 128 + l16) * 64];
    const f16* aB1 = &sA[1][(wm * 128 + l16) * 64];
    const f16* bB0 = &sB[0][(wn * 64 + l16) * 64];
    const f16* bB1 = &sB[1][(wn * 64 + l16) * 64];

    f16x8 afr[4][2], bfr[2][2][2];
    f32x4 acc[8][4] = {};

#define LDA(PB, MH) do { \
    _Pragma("unroll") \
    for (int ii_ = 0; ii_ < 4; ii_++) { \
        afr[ii_][0] = *(const f16x8*)(PB + ((MH) * 4 + ii_) * 1024 + go0); \
        afr[ii_][1] = *(const f16x8*)(PB + ((MH) * 4 + ii_) * 1024 + go1); \
    } \
} while (0)

#define LDB(PB, NH) do { \
    _Pragma("unroll") \
    for (int jj_ = 0; jj_ < 2; jj_++) { \
        bfr[NH][jj_][0] = *(const f16x8*)(PB + ((NH) * 2 + jj_) * 1024 + go0); \
        bfr[NH][jj_][1] = *(const f16x8*)(PB + ((NH) * 2 + jj_) * 1024 + go1); \
    } \
} while (0)

#define QMFMA(MH, NH) do { \
    __builtin_amdgcn_s_setprio(1); \
    _Pragma("unroll") \
    for (int ii_ = 0; ii_ < 4; ii_++) \
    _Pragma("unroll") \
    for (int jj_ = 0; jj_ < 2; jj_++) { \
        acc[(MH)*4+ii_][(NH)*2+jj_] = __builtin_amdgcn_mfma_f32_16x16x32_f16(afr[ii_][0], bfr[NH][jj_][0], acc[(MH)*4+ii_][(NH)*2+jj_], 0, 0, 0); \
        acc[(MH)*4+ii_][(NH)*2+jj_] = __builtin_amdgcn_mfma_f32_16x16x32_f16(afr[ii_][1], bfr[NH][jj_][1], acc[(MH)*4+ii_][(NH)*2+jj_], 0, 0, 0); \
    } \
    __builtin_amdgcn_s_setprio(0); \
} while (0)

    STG_A(0, 0); STG_B(0, 0);
    STG_A(1, 1); STG_B(1, 1);
    VMW8();
    BARX();

#pragma unroll 1
    for (int it = 0; it < 16; it++) {
        int kt2 = 2 * it + 2; if (kt2 > 31) kt2 = 31;
        int kt3 = 2 * it + 3; if (kt3 > 31) kt3 = 31;
        // even tile (buf0)
        LDA(aB0, 0); LDB(bB0, 0);
        BARX(); LGKM0(); QMFMA(0, 0); BARX();
        LDB(bB0, 1);
        BARX(); LGKM0(); QMFMA(0, 1); BARX();
        LDA(aB0, 1); STG_B(0, kt2);     // B-buf0 dead after phase-2 barrier
        BARX(); LGKM0(); QMFMA(1, 0); BARX();
        STG_A(0, kt2);                  // A-buf0 dead after phase-3 barrier
        VMW8();                         // drain odd tile (read next, phases 5-7)
        BARX(); QMFMA(1, 1); BARX();
        // odd tile (buf1)
        LDA(aB1, 0); LDB(bB1, 0);
        BARX(); LGKM0(); QMFMA(0, 0); BARX();
        LDB(bB1, 1);
        BARX(); LGKM0(); QMFMA(0, 1); BARX();
        LDA(aB1, 1); STG_B(1, kt3);
        BARX(); LGKM0(); QMFMA(1, 0); BARX();
        STG_A(1, kt3);
        VMW8();
        BARX(); QMFMA(1, 1); BARX();
    }
    asm volatile("s_waitcnt vmcnt(0)" ::: "memory");

    long rb = (long)bm * 256 + wm * 128 + quad * 4;
    f16* dst; long cw, cb; float sc = 1.f;
    if (bn < 4)      { dst = h0; cw = 1024; cb = (long)bn * 256;       sc = 0.125f; }
    else if (bn < 8) { dst = h1; cw = 1024; cb = (long)(bn - 4) * 256; }
    else             { dst = h2; cw = 2048; cb = (long)(bn - 8) * 256; }
    long cbase = cb + wn * 64 + l16;
#pragma unroll
    for (int i = 0; i < 8; i++)
#pragma unroll
        for (int j = 0; j < 4; j++)
#pragma unroll
            for (int r = 0; r < 4; r++) {
                float x = acc[i][j][r];
                x = x / (1.f + __expf(-x)) * sc;
                dst[(rb + i * 16 + r) * cw + cbase + j * 16] = (f16)x;
            }
#undef STG_A
#undef STG_B
#undef LDA
#undef LDB
#undef QMFMA
}

// ---------------- 128x256 f16 GEMM (out): full-chip fill at N=2048 ----------------
__global__ __launch_bounds__(512, 2) void gemm128o(const f16* __restrict__ A,
                                                   const f16* __restrict__ Bt,
                                                   float* __restrict__ o0) {
    __shared__ __align__(16) f16 sAb[16384];   // 2 bufs x [128][64] swizzled
    __shared__ __align__(16) f16 sBb[32768];   // 2 bufs x [256][64] swizzled
    int tid = threadIdx.x;
    int wave = tid >> 6, lane = tid & 63;
    int quad = lane >> 4, l16 = lane & 15;
    int wm = wave >> 2, wn = wave & 3;         // 2M x 4N

    int cpx = (int)gridDim.x >> 3;
    int wid = ((int)blockIdx.x & 7) * cpx + ((int)blockIdx.x >> 3);
    int bm = wid & 31, bn = wid >> 5;

    int srow = tid >> 3;
    int gsrc = ((tid & 7) ^ (srow & 7)) * 8;
    const f16* Asrc = A  + ((long)bm * 128 + srow) * 2048 + gsrc;
    const f16* Bsrc = Bt + ((long)bn * 256 + srow) * 2048 + gsrc;

#define STAGE(P, KT) do { \
    _Pragma("unroll") \
    for (int q_ = 0; q_ < 2; q_++) \
        gl_lds16(Asrc + (KT) * 64 + (long)q_ * 64 * 2048, sAb + (P) * 8192 + tid * 8 + q_ * 4096); \
    _Pragma("unroll") \
    for (int q_ = 0; q_ < 4; q_++) \
        gl_lds16(Bsrc + (KT) * 64 + (long)q_ * 64 * 2048, sBb + (P) * 16384 + tid * 8 + q_ * 4096); \
} while (0)

    int go0 = (quad ^ (l16 & 7)) * 8;
    int go1 = go0 ^ 32;
    const f16* pA0 = sAb + (wm * 64 + l16) * 64 + go0;
    const f16* pA1 = sAb + (wm * 64 + l16) * 64 + go1;
    const f16* pB0 = sBb + (wn * 64 + l16) * 64 + go0;
    const f16* pB1 = sBb + (wn * 64 + l16) * 64 + go1;

    f16x8 aX[4], bX[4], aY[4], bY[4];
    f32x4 acc[4][4] = {};

#define RDA(D, PTR, POFF) do { \
    D[0] = *(const f16x8*)((PTR) + (POFF)); \
    D[1] = *(const f16x8*)((PTR) + (POFF) + 1024); \
    D[2] = *(const f16x8*)((PTR) + (POFF) + 2048); \
    D[3] = *(const f16x8*)((PTR) + (POFF) + 3072); \
} while (0)

#define MM(AS, BS) do { \
    __builtin_amdgcn_s_setprio(1); \
    _Pragma("unroll") \
    for (int m_ = 0; m_ < 4; m_++) \
    _Pragma("unroll") \
    for (int n_ = 0; n_ < 4; n_++) \
        acc[m_][n_] = __builtin_amdgcn_mfma_f32_16x16x32_f16(AS[m_], BS[n_], acc[m_][n_], 0, 0, 0); \
    __builtin_amdgcn_s_setprio(0); \
} while (0)

    STAGE(0, 0);
    STAGE(1, 1);
    VMW6();
    BARX();
    RDA(aX, pA0, 0); RDA(bX, pB0, 0);

#pragma unroll 1
    for (int it = 0; it < 16; it++) {
        int c2 = 2 * it + 2; if (c2 > 31) c2 = 31;
        int c3 = 2 * it + 3; if (c3 > 31) c3 = 31;
        RDA(aY, pA1, 0); RDA(bY, pB1, 0);
        MM(aX, bX);
        LGKM0();
        BARX();
        STAGE(0, c2);
        VMW6();
        BARX();
        RDA(aX, pA0, 8192); RDA(bX, pB0, 16384);
        MM(aY, bY);
        RDA(aY, pA1, 8192); RDA(bY, pB1, 16384);
        MM(aX, bX);
        LGKM0();
        BARX();
        STAGE(1, c3);
        VMW6();
        BARX();
        RDA(aX, pA0, 0); RDA(bX, pB0, 0);
        MM(aY, bY);
    }
    asm volatile("s_waitcnt vmcnt(0)" ::: "memory");

    long rb = (long)bm * 128 + wm * 64 + quad * 4;
    long cbase = (long)bn * 256 + wn * 64 + l16;
#pragma unroll
    for (int m = 0; m < 4; m++)
#pragma unroll
        for (int n = 0; n < 4; n++)
#pragma unroll
            for (int r = 0; r < 4; r++)
                o0[(rb + m * 16 + r) * 2048 + cbase + n * 16] = acc[m][n][r];
#undef STAGE
#undef RDA
#undef MM
}

// ---------------- prep2: vtrans + gk_cum ----------------
// blk [0,1024): v [4096][2048] -> vT [2048][4096]
// blk [1024,2048): t_gk -> logsigmoid -> cumsum G + dec
__global__ __launch_bounds__(256) void prep2(const u16* __restrict__ v,
                                             u16* __restrict__ vT,
                                             const float* __restrict__ t_gk,
                                             const float* __restrict__ Wgk2,
                                             const float* __restrict__ bgk2,
                                             float* __restrict__ G,
                                             float* __restrict__ dec) {
    __shared__ __align__(16) char smem_raw[33280];
    int blk = blockIdx.x;
    int tid = threadIdx.x;
    if (blk < 1024) {
        uint32_t* su = (uint32_t*)smem_raw;   // 128*65*4 = 33280 B
        int t0 = (blk >> 5) * 128;
        int e0 = (blk & 31) * 64;
#pragma unroll
        for (int i = 0; i < 4; i++) {
            int tr = i * 32 + (tid >> 3);
            int ec = (tid & 7) * 8;
            u16x8 g = *(const u16x8*)(v + (long)(t0 + tr) * 2048 + e0 + ec);
#pragma unroll
            for (int j = 0; j < 8; j++) su[tr * 65 + ec + j] = g[j];
        }
        __syncthreads();
#pragma unroll
        for (int i = 0; i < 2; i++) {
            int er = i * 32 + (tid >> 3);
            int tch = (tid & 7) * 16;
            u16x8 o0, o1;
#pragma unroll
            for (int j = 0; j < 8; j++) {
                o0[j] = (u16)su[(tch + j) * 65 + er];
                o1[j] = (u16)su[(tch + 8 + j) * 65 + er];
            }
            u16* dst = vT + (long)(e0 + er) * 4096 + t0 + tch;
            *(u16x8*)dst = o0;
            *(u16x8*)(dst + 8) = o1;
        }
    } else {
        float* sT = (float*)smem_raw;          // 4 KB
        float* sW = sT + 1024;                 // 4 KB
        float* sb = sW + 1024;                 // 256 B
        float* sG = sb + 64;                   // 16 KB
        int bq = blk - 1024;
        int c = bq & 31, h = (bq >> 5) & 15, b = bq >> 9;
        long rowbase = (long)b * Tq + c * 64;
        {
            int idx = tid * 4;
            *(float4*)&sT[idx] = *(const float4*)(t_gk + rowbase * 16 + idx);
            int rr = idx >> 6, dd = idx & 63;
            *(float4*)&sW[idx] = *(const float4*)(Wgk2 + rr * 1024 + h * 64 + dd);
        }
        if (tid < 64) sb[tid] = bgk2[h * 64 + tid];
        __syncthreads();
        int tquad = tid >> 4, dgrp = tid & 15;
        float4 bg4 = *(float4*)&sb[dgrp * 4];
#pragma unroll
        for (int j = 0; j < 4; j++) {
            int t = tquad * 4 + j;
            float4 z = bg4;
#pragma unroll
            for (int rr = 0; rr < 16; rr++) {
                float tv = sT[t * 16 + rr];
                float4 wv = *(float4*)&sW[rr * 64 + dgrp * 4];
                z.x += tv * wv.x; z.y += tv * wv.y; z.z += tv * wv.z; z.w += tv * wv.w;
            }
            float4 o;
            o.x = (fminf(z.x, 0.f) - log1pf(__expf(-fabsf(z.x)))) * 0.0625f;
            o.y = (fminf(z.y, 0.f) - log1pf(__expf(-fabsf(z.y)))) * 0.0625f;
            o.z = (fminf(z.z, 0.f) - log1pf(__expf(-fabsf(z.z)))) * 0.0625f;
            o.w = (fminf(z.w, 0.f) - log1pf(__expf(-fabsf(z.w)))) * 0.0625f;
            *(float4*)&sG[t * 64 + dgrp * 4] = o;
        }
        __syncthreads();
        if (tid < 64) {
            float run = 0.f;
            for (int t = 0; t < 64; t++) { run += sG[t * 64 + tid]; sG[t * 64 + tid] = run; }
            dec[bq * 64 + tid] = __expf(run);
        }
        __syncthreads();
        float* Gb = G + (long)bq * 4096;
#pragma unroll
        for (int i = 0; i < 4; i++) {
            int f = tid + i * 256;
            *(float4*)(Gb + f * 4) = *(float4*)&sG[f * 4];
        }
    }
}

// ---------------- GLA pass 1: U^T[e][d] per chunk ----------------
#define ST 68
__global__ __launch_bounds__(256) void gla_pass1(const f16* __restrict__ kbuf,
                                                 const f16* __restrict__ vh,
                                                 const float* __restrict__ G,
                                                 float* __restrict__ U) {
    __shared__ float sG[64 * ST];
    __shared__ float sK[64 * ST];
    int blk = blockIdx.x;
    int c = blk & 31, h = (blk >> 5) & 15, b = blk >> 9;
    int tid = threadIdx.x;
    long rowbase = (long)b * Tq + c * 64;
    const float* Gb = G + (long)blk * 4096;
#pragma unroll
    for (int i = 0; i < 4; i++) {
        int f = tid + i * 256;
        float4 v = *(const float4*)(Gb + f * 4);
        int t = f >> 4, d0 = (f & 15) * 4;
        *(float4*)&sG[t * ST + d0] = v;
    }
    __syncthreads();
#pragma unroll
    for (int i = 0; i < 16; i++) {
        int idx = tid + i * 256;
        int t = idx >> 6, d = idx & 63;
        float gl = sG[63 * ST + d];
        sK[t * ST + d] = (float)kbuf[(rowbase + t) * 1024 + h * 64 + d] * __expf(gl - sG[t * ST + d]);
    }
    __syncthreads();
    int ty = tid >> 4, tx = tid & 15;
    float acc[4][8] = {};
    const f16* vb = vh + rowbase * 2048 + h * 128 + tx * 8;
    for (int t = 0; t < 64; t++) {
        float kd[4];
        *(float4*)&kd[0] = *(float4*)&sK[t * ST + ty * 4];
        f16x8 vv = *(const f16x8*)(vb + (long)t * 2048);
        float ve[8];
#pragma unroll
        for (int e = 0; e < 8; e++) ve[e] = (float)vv[e];
#pragma unroll
        for (int r = 0; r < 4; r++)
#pragma unroll
            for (int e = 0; e < 8; e++) acc[r][e] += kd[r] * ve[e];
    }
    // transposed store: U^T[e][d]
    float* Ub = U + (long)blk * 8192;
#pragma unroll
    for (int r = 0; r < 4; r++) {
        int d = ty * 4 + r;
#pragma unroll
        for (int e8 = 0; e8 < 8; e8++)
            Ub[(tx * 8 + e8) * 64 + d] = acc[r][e8];
    }
}

// ---------------- GLA pass 2: scan; full-fill 256 blocks, float4 lanes ----------------
__global__ __launch_bounds__(256) void gla_pass2(const float* __restrict__ U,
                                                 const float* __restrict__ dec,
                                                 f16* __restrict__ ShT) {
    int bh = blockIdx.x >> 3;
    int tid = threadIdx.x;
    int e = (blockIdx.x & 7) * 16 + (tid >> 4);
    int d0 = (tid & 15) * 4;
    float4 Sa = {0.f, 0.f, 0.f, 0.f};
    for (int c = 0; c < NCq; c++) {
        long base = ((long)(bh * 32 + c) * 128 + e) * 64 + d0;
        float4 u0 = *(const float4*)(U + base);
        float4 dc0 = *(const float4*)(dec + (bh * 32 + c) * 64 + d0);
        f16x4 sh;
        sh[0] = (f16)Sa.x; sh[1] = (f16)Sa.y; sh[2] = (f16)Sa.z; sh[3] = (f16)Sa.w;
        *(f16x4*)(ShT + base) = sh;
        Sa.x = Sa.x * dc0.x + u0.x; Sa.y = Sa.y * dc0.y + u0.y;
        Sa.z = Sa.z * dc0.z + u0.z; Sa.w = Sa.w * dc0.w + u0.w;
    }
}

// ---------------- GLA pass 3 (MFMA) ----------------
#define GRD(row, kslot) (((row) << 6) + ((((kslot) ^ ((row) & 7))) << 3))
__global__ __launch_bounds__(256) void gla_pass3(const f16* __restrict__ qb,
                                                 const f16* __restrict__ kb,
                                                 const float* __restrict__ G,
                                                 const float* __restrict__ t_g,
                                                 const float* __restrict__ Wg2,
                                                 const float* __restrict__ bg2,
                                                 const float* __restrict__ gnw,
                                                 const f16* __restrict__ ShT,
                                                 const f16* __restrict__ vT,
                                                 f16* __restrict__ Oh) {
    __shared__ __align__(16) f16 sQg[4096];   // [t 64][d 64] swz
    __shared__ __align__(16) f16 sKg[4096];   // [t' 64][d 64] swz
    __shared__ __align__(16) f16 sAh[4096];   // [t 64][t' 64] swz
    __shared__ __align__(16) f16 sST[8192];   // [e 128][d 64] swz
    __shared__ __align__(16) f16 sVT[8192];   // [e 128][t' 64] swz
    __shared__ float sWg[16 * 128];
    __shared__ float sbg[128];
    int blk = blockIdx.x;
    int c = blk & 31, h = (blk >> 5) & 15, b = blk >> 9;
    int tid = threadIdx.x;
    long rowbase = (long)b * Tq + c * 64;

#pragma unroll
    for (int i = 0; i < 4; i++) {
        int s = tid + i * 256;
        int e = s >> 3, gp = s & 7;
        int gl = gp ^ (e & 7);
        gl_lds16(ShT + (long)blk * 8192 + e * 64 + gl * 8, sST + s * 8);
        gl_lds16(vT + (long)(h * 128 + e) * 4096 + rowbase + gl * 8, sVT + s * 8);
    }
#pragma unroll
    for (int i = 0; i < 2; i++) {
        int idx = tid * 4 + i * 1024;
        int rr = idx >> 7, ee = idx & 127;
        *(float4*)&sWg[idx] = *(const float4*)(Wg2 + (long)rr * 2048 + h * 128 + ee);
    }
    if (tid < 128) sbg[tid] = bg2[h * 128 + tid];
#pragma unroll
    for (int i = 0; i < 4; i++) {
        int f = tid + i * 256;
        int t = f >> 4, gi = f & 15;
        float4 G4 = *(const float4*)(G + (long)blk * 4096 + f * 4);
        long gb = (rowbase + t) * 1024 + h * 64 + gi * 4;
        f16x4 q4 = *(const f16x4*)(qb + gb);
        f16x4 k4 = *(const f16x4*)(kb + gb);
        f16x4 qh, kh;
        float ex;
        ex = __expf(G4.x); qh[0] = (f16)((float)q4[0] * ex); kh[0] = (f16)((float)k4[0] / ex);
        ex = __expf(G4.y); qh[1] = (f16)((float)q4[1] * ex); kh[1] = (f16)((float)k4[1] / ex);
        ex = __expf(G4.z); qh[2] = (f16)((float)q4[2] * ex); kh[2] = (f16)((float)k4[2] / ex);
        ex = __expf(G4.w); qh[3] = (f16)((float)q4[3] * ex); kh[3] = (f16)((float)k4[3] / ex);
        int w = (t << 6) + ((((gi >> 1) ^ (t & 7))) << 3) + ((gi & 1) << 2);
        *(f16x4*)(sQg + w) = qh;
        *(f16x4*)(sKg + w) = kh;
    }
    __syncthreads();

    int wv = tid >> 6, lane = tid & 63;
    int quad = lane >> 4, l16 = lane & 15;
    int trow = wv * 16 + l16;

    f16x8 afq[2];
    afq[0] = *(const f16x8*)(sQg + GRD(trow, quad));
    afq[1] = *(const f16x8*)(sQg + GRD(trow, 4 + quad));
#pragma unroll
    for (int j4 = 0; j4 < 4; j4++) {
        int tc = j4 * 16 + l16;
        f16x8 bk0 = *(const f16x8*)(sKg + GRD(tc, quad));
        f16x8 bk1 = *(const f16x8*)(sKg + GRD(tc, 4 + quad));
        f32x4 ca = {};
        ca = __builtin_amdgcn_mfma_f32_16x16x32_f16(afq[0], bk0, ca, 0, 0, 0);
        ca = __builtin_amdgcn_mfma_f32_16x16x32_f16(afq[1], bk1, ca, 0, 0, 0);
#pragma unroll
        for (int r = 0; r < 4; r++) {
            int tr = wv * 16 + quad * 4 + r;
            int tcw = j4 * 16 + l16;
            f16 av = (tcw <= tr) ? (f16)ca[r] : (f16)0.f;
            sAh[(tr << 6) + ((((tcw >> 3) ^ (tr & 7))) << 3) + (tcw & 7)] = av;
        }
    }

    f16x8 afa[2];
    afa[0] = *(const f16x8*)(sAh + GRD(trow, quad));
    afa[1] = *(const f16x8*)(sAh + GRD(trow, 4 + quad));
    f32x4 acc[8];
#pragma unroll
    for (int et = 0; et < 8; et++) {
        int e = et * 16 + l16;
        f16x8 bs0 = *(const f16x8*)(sST + GRD(e, quad));
        f16x8 bs1 = *(const f16x8*)(sST + GRD(e, 4 + quad));
        f16x8 bv0 = *(const f16x8*)(sVT + GRD(e, quad));
        f16x8 bv1 = *(const f16x8*)(sVT + GRD(e, 4 + quad));
        f32x4 cc = {};
        cc = __builtin_amdgcn_mfma_f32_16x16x32_f16(afq[0], bs0, cc, 0, 0, 0);
        cc = __builtin_amdgcn_mfma_f32_16x16x32_f16(afq[1], bs1, cc, 0, 0, 0);
        cc = __builtin_amdgcn_mfma_f32_16x16x32_f16(afa[0], bv0, cc, 0, 0, 0);
        cc = __builtin_amdgcn_mfma_f32_16x16x32_f16(afa[1], bv1, cc, 0, 0, 0);
        acc[et] = cc;
    }

    float gw[8], bgv[8];
#pragma unroll
    for (int et = 0; et < 8; et++) {
        gw[et]  = gnw[et * 16 + l16];
        bgv[et] = sbg[et * 16 + l16];
    }
#pragma unroll
    for (int half = 0; half < 2; half++) {
        float tg[2][16];
#pragma unroll
        for (int rh = 0; rh < 2; rh++) {
            int t = wv * 16 + quad * 4 + half * 2 + rh;
            const float* tgp = t_g + (rowbase + t) * 16;
#pragma unroll
            for (int q4 = 0; q4 < 4; q4++)
                *(float4*)&tg[rh][q4 * 4] = *(const float4*)(tgp + q4 * 4);
        }
        float g[2][8];
#pragma unroll
        for (int rh = 0; rh < 2; rh++)
#pragma unroll
            for (int et = 0; et < 8; et++) g[rh][et] = bgv[et];
#pragma unroll
        for (int rr = 0; rr < 16; rr++) {
#pragma unroll
            for (int et = 0; et < 8; et++) {
                float wv_ = sWg[rr * 128 + et * 16 + l16];
                g[0][et] += tg[0][rr] * wv_;
                g[1][et] += tg[1][rr] * wv_;
            }
        }
#pragma unroll
        for (int rh = 0; rh < 2; rh++) {
            int r = half * 2 + rh;
            int t = wv * 16 + quad * 4 + r;
            float ss = 0.f;
#pragma unroll
            for (int et = 0; et < 8; et++) ss += acc[et][r] * acc[et][r];
            ss += __shfl_xor(ss, 1);
            ss += __shfl_xor(ss, 2);
            ss += __shfl_xor(ss, 4);
            ss += __shfl_xor(ss, 8);
            float scale = rsqrtf(ss * (1.f / 128.f) + 1e-5f);
            long off = (rowbase + t) * 2048 + h * 128 + l16;
#pragma unroll
            for (int et = 0; et < 8; et++) {
                float y = acc[et][r] * scale * gw[et] / (1.f + __expf(-g[rh][et]));
                Oh[off + et * 16] = (f16)y;
            }
        }
    }
}

extern "C" void kernel_launch(void* const* d_in, const int* in_sizes, int n_in,
                              void* d_out, int out_size, void* d_ws, size_t ws_size,
                              hipStream_t stream) {
    const float* hs   = (const float*)d_in[0];
    const float* Wq   = (const float*)d_in[1];
    const float* Wk   = (const float*)d_in[2];
    const float* Wv   = (const float*)d_in[3];
    const float* Wgk1 = (const float*)d_in[4];
    const float* Wgk2 = (const float*)d_in[5];
    const float* bgk2 = (const float*)d_in[6];
    const float* Wg1  = (const float*)d_in[7];
    const float* Wg2  = (const float*)d_in[8];
    const float* bg2  = (const float*)d_in[9];
    const float* Wo   = (const float*)d_in[10];
    const float* gnw  = (const float*)d_in[11];

    char* w = (char*)d_ws;
    auto alloc = [&](size_t bytes) {
        char* p = w; w += (bytes + 255) & ~size_t(255); return (void*)p;
    };
    f16*   Xh     = (f16*)  alloc((size_t)Mq * Dq * 2);        // 16 MB (reused for O)
    f16*   WqkvT  = (f16*)  alloc((size_t)4224 * 2048 * 2);    // 17.3 MB [q|k|v]
    f16*   WoT    = (f16*)  alloc((size_t)2048 * 2048 * 2);    // 8 MB
    f16*   qb     = (f16*)  alloc((size_t)Mq * 1024 * 2);      // 8 MB (f16)
    f16*   kb     = (f16*)  alloc((size_t)Mq * 1024 * 2);      // 8 MB (f16)
    f16*   vhb    = (f16*)  alloc((size_t)Mq * 2048 * 2);      // 16 MB (v row-major)
    f16*   vTb    = (f16*)  alloc((size_t)Mq * 2048 * 2);      // 16 MB (v^T)
    float* t_gk   = (float*)alloc((size_t)Mq * 16 * 4);
    float* t_g    = (float*)alloc((size_t)Mq * 16 * 4);
    float* Ut     = (float*)alloc((size_t)NBH * NCq * 8192 * 4); // 33.5 MB (U^T)
    f16*   ShT    = (f16*)  alloc((size_t)NBH * NCq * 8192 * 2); // 16.8 MB (S^T f16)
    float* dec    = (float*)alloc((size_t)NBH * NCq * 64 * 4);
    float* Gbuf   = (float*)alloc((size_t)NBH * NCq * 4096 * 4); // 16.8 MB

    // prep1: weight transposes (12288) + hs conv (4096) + lowrank (256)
    prep1<<<16640, 256, 0, stream>>>(Wq, Wk, Wv, Wo, hs, Wgk1, Wg1,
                                     WqkvT, WoT, Xh, t_gk, t_g);

    // fused q|k|v GEMM: 256x256 tiles, 16x16 = 256 blocks (exact CU fill)
    gemm256q<<<256, 512, 0, stream>>>(Xh, WqkvT, qb, kb, vhb);

    // prep2: vtrans (1024) + gk_cum (1024)
    prep2<<<2048, 256, 0, stream>>>((const u16*)vhb, (u16*)vTb,
                                    t_gk, Wgk2, bgk2, Gbuf, dec);

    gla_pass1<<<NBH * NCq, 256, 0, stream>>>(kb, vhb, Gbuf, Ut);
    gla_pass2<<<NBH * 8, 256, 0, stream>>>(Ut, dec, ShT);
    gla_pass3<<<NBH * NCq, 256, 0, stream>>>(qb, kb, Gbuf, t_g, Wg2, bg2, gnw, ShT, vTb, Xh);

    // out GEMM: 128x256 tiles, 32x8 = 256 blocks (exact CU fill)
    gemm128o<<<256, 512, 0, stream>>>(Xh, WoT, (float*)d_out);
}

// Round 9
// 407.699 us; speedup vs baseline: 1.0282x; 1.0282x over previous
//
#include <hip/hip_runtime.h>
#include <cstdint>

// Problem constants
#define Bq   2
#define Tq   2048
#define Dq   2048
#define Hq   16
#define DKq  64
#define DVq  128
#define Cq   64          // chunk len
#define NCq  32          // chunks
#define Mq   4096        // B*T
#define NBH  32          // B*H

typedef _Float16 f16;
typedef f16 f16x4 __attribute__((ext_vector_type(4)));
typedef f16 f16x8 __attribute__((ext_vector_type(8)));
typedef float f32x4 __attribute__((ext_vector_type(4)));
typedef unsigned short u16;
typedef u16 u16x8 __attribute__((ext_vector_type(8)));

__device__ __forceinline__ void gl_lds16(const void* g, void* l) {
    __builtin_amdgcn_global_load_lds(
        (const __attribute__((address_space(1))) uint32_t*)g,
        (__attribute__((address_space(3))) uint32_t*)l, 16, 0, 0);
}

#define BARX()   asm volatile("s_barrier" ::: "memory")
#define LGKM0()  asm volatile("s_waitcnt lgkmcnt(0)" ::: "memory")
#define VMW8()   asm volatile("s_waitcnt vmcnt(8)" ::: "memory")
#define VMW6()   asm volatile("s_waitcnt vmcnt(6)" ::: "memory")

// ---------------- merged weight transpose to f16 (64x64 tiles, 3072 blocks) ----------------
// 16 elems/thread (was 4): fewer blocks, more work each, same coalescing.
__global__ __launch_bounds__(256) void trans_all(const float* __restrict__ Wq,
                                                 const float* __restrict__ Wk,
                                                 const float* __restrict__ Wv,
                                                 const float* __restrict__ Wo,
                                                 f16* __restrict__ Qkv, f16* __restrict__ WoT) {
    __shared__ float sh[64 * 65];   // [n 64][k 65] (pad breaks pow-2 stride)
    int blk = blockIdx.x;
    int tid = threadIdx.x;
    const float* W; f16* Dh; int N, nt, kt; long rowoff;
    if (blk < 512)       { W = Wq; N = 1024; int t = blk;        nt = t & 15; kt = t >> 4; Dh = Qkv; rowoff = 0; }
    else if (blk < 1024) { W = Wk; N = 1024; int t = blk - 512;  nt = t & 15; kt = t >> 4; Dh = Qkv; rowoff = 1024; }
    else if (blk < 2048) { W = Wv; N = 2048; int t = blk - 1024; nt = t & 31; kt = t >> 5; Dh = Qkv; rowoff = 2048; }
    else                 { W = Wo; N = 2048; int t = blk - 2048; nt = t & 31; kt = t >> 5; Dh = WoT; rowoff = 0; }
    int k0 = kt * 64, n0 = nt * 64;
    int kr = tid >> 4, nc = (tid & 15) * 4;
#pragma unroll
    for (int p = 0; p < 4; p++) {
        int k = kr + p * 16;
        float4 w4 = *(const float4*)(W + (long)(k0 + k) * N + n0 + nc);
        sh[(nc + 0) * 65 + k] = w4.x;
        sh[(nc + 1) * 65 + k] = w4.y;
        sh[(nc + 2) * 65 + k] = w4.z;
        sh[(nc + 3) * 65 + k] = w4.w;
    }
    __syncthreads();
    int nr = tid >> 3, kch = (tid & 7) * 8;
#pragma unroll
    for (int p = 0; p < 2; p++) {
        int n = nr + p * 32;
        f16x8 o;
#pragma unroll
        for (int j = 0; j < 8; j++) o[j] = (f16)sh[n * 65 + kch + j];
        *(f16x8*)(Dh + (rowoff + n0 + n) * 2048L + k0 + kch) = o;
    }
}

// ---------------- pure f32 -> f16 convert ----------------
__global__ __launch_bounds__(256) void hs_conv(const float* __restrict__ in,
                                               f16* __restrict__ out) {
    long i = ((long)blockIdx.x * 256 + threadIdx.x) * 8;
    float4 a = *(const float4*)(in + i);
    float4 b = *(const float4*)(in + i + 4);
    f16x8 h;
    h[0] = (f16)a.x; h[1] = (f16)a.y; h[2] = (f16)a.z; h[3] = (f16)a.w;
    h[4] = (f16)b.x; h[5] = (f16)b.y; h[6] = (f16)b.z; h[7] = (f16)b.w;
    *(f16x8*)(out + i) = h;
}

// ---------------- low-rank t_gk / t_g ----------------
__global__ __launch_bounds__(256) void lowrank_tg(const float* __restrict__ hs,
                                                  const float* __restrict__ Wgk1,
                                                  const float* __restrict__ Wg1,
                                                  float* __restrict__ t_gk,
                                                  float* __restrict__ t_g) {
    __shared__ float sW[512 * 32];       // 64 KB, granule-swizzled
    int tid = threadIdx.x;
    int blk = blockIdx.x;
    int r = tid >> 4, seg = tid & 15;
    long row = (long)blk * 16 + r;
    float acc[32];
#pragma unroll
    for (int c = 0; c < 32; c++) acc[c] = 0.f;
    for (int kc = 0; kc < 2048; kc += 512) {
        __syncthreads();
#pragma unroll
        for (int i = 0; i < 16; i++) {
            int s = tid + i * 256;
            int k = s >> 3, q = s & 7;
            float4 w = (q < 4) ? *(const float4*)(Wgk1 + (long)(kc + k) * 16 + q * 4)
                               : *(const float4*)(Wg1  + (long)(kc + k) * 16 + (q - 4) * 4);
            int qs = q ^ ((k >> 5) & 7);
            *(float4*)&sW[k * 32 + qs * 4] = w;
        }
        __syncthreads();
        const float* hp = hs + row * 2048 + kc + seg * 32;
        int xr = seg & 7;
#pragma unroll
        for (int k4 = 0; k4 < 8; k4++) {
            float4 hv = *(const float4*)(hp + k4 * 4);
            float hvv[4] = {hv.x, hv.y, hv.z, hv.w};
#pragma unroll
            for (int u = 0; u < 4; u++) {
                int k = seg * 32 + k4 * 4 + u;
                const float* wr = &sW[k * 32];
#pragma unroll
                for (int q = 0; q < 8; q++) {
                    float4 wv = *(const float4*)(wr + ((q ^ xr) * 4));
                    acc[q * 4 + 0] += hvv[u] * wv.x;
                    acc[q * 4 + 1] += hvv[u] * wv.y;
                    acc[q * 4 + 2] += hvv[u] * wv.z;
                    acc[q * 4 + 3] += hvv[u] * wv.w;
                }
            }
        }
    }
#pragma unroll
    for (int c = 0; c < 32; c++) {
        acc[c] += __shfl_xor(acc[c], 1);
        acc[c] += __shfl_xor(acc[c], 2);
        acc[c] += __shfl_xor(acc[c], 4);
        acc[c] += __shfl_xor(acc[c], 8);
    }
    if (seg == 0) {
        float4 a;
        a.x = acc[0];  a.y = acc[1];  a.z = acc[2];  a.w = acc[3];  *(float4*)(t_gk + row * 16)     = a;
        a.x = acc[4];  a.y = acc[5];  a.z = acc[6];  a.w = acc[7];  *(float4*)(t_gk + row * 16 + 4) = a;
        a.x = acc[8];  a.y = acc[9];  a.z = acc[10]; a.w = acc[11]; *(float4*)(t_gk + row * 16 + 8) = a;
        a.x = acc[12]; a.y = acc[13]; a.z = acc[14]; a.w = acc[15]; *(float4*)(t_gk + row * 16 + 12)= a;
        a.x = acc[16]; a.y = acc[17]; a.z = acc[18]; a.w = acc[19]; *(float4*)(t_g + row * 16)      = a;
        a.x = acc[20]; a.y = acc[21]; a.z = acc[22]; a.w = acc[23]; *(float4*)(t_g + row * 16 + 4)  = a;
        a.x = acc[24]; a.y = acc[25]; a.z = acc[26]; a.w = acc[27]; *(float4*)(t_g + row * 16 + 8)  = a;
        a.x = acc[28]; a.y = acc[29]; a.z = acc[30]; a.w = acc[31]; *(float4*)(t_g + row * 16 + 12) = a;
    }
}

// ---------------- 256x256 8-phase f16 GEMM (qkv): round-7 measured 81.4 us ----------------
__global__ __launch_bounds__(512, 2) void gemm256q(const f16* __restrict__ A,
                                                   const f16* __restrict__ Bt,
                                                   f16* __restrict__ h0,
                                                   f16* __restrict__ h1,
                                                   f16* __restrict__ h2) {
    __shared__ __align__(16) f16 sA[2][16384];
    __shared__ __align__(16) f16 sB[2][16384];
    int tid = threadIdx.x;
    int wave = tid >> 6, lane = tid & 63;
    int quad = lane >> 4, l16 = lane & 15;
    int wm = wave >> 2, wn = wave & 3;

    int cpx = (int)gridDim.x >> 3;
    int wid = ((int)blockIdx.x & 7) * cpx + ((int)blockIdx.x >> 3);
    int bm = wid & 15, bn = wid >> 4;

    const f16* Ab = A  + (long)bm * 256 * 2048;
    const f16* Bb = Bt + (long)bn * 256 * 2048;

    int srow = tid >> 3;
    int gsrc = ((tid & 7) ^ (srow & 7)) * 8;
    const f16* Asrc = Ab + (long)srow * 2048 + gsrc;
    const f16* Bsrc = Bb + (long)srow * 2048 + gsrc;

#define STAGE(P, KT) do { \
    const f16* as_ = Asrc + (KT) * 64; \
    const f16* bs_ = Bsrc + (KT) * 64; \
    f16* la_ = &sA[P][tid * 8]; \
    f16* lb_ = &sB[P][tid * 8]; \
    _Pragma("unroll") \
    for (int q_ = 0; q_ < 4; q_++) gl_lds16(as_ + (long)q_ * 64 * 2048, la_ + q_ * 4096); \
    _Pragma("unroll") \
    for (int q_ = 0; q_ < 4; q_++) gl_lds16(bs_ + (long)q_ * 64 * 2048, lb_ + q_ * 4096); \
} while (0)

    int go0 = (quad ^ (l16 & 7)) * 8;
    int go1 = go0 ^ 32;
    const f16* aB0 = &sA[0][(wm * 128 + l16) * 64];
    const f16* aB1 = &sA[1][(wm * 128 + l16) * 64];
    const f16* bB0 = &sB[0][(wn * 64 + l16) * 64];
    const f16* bB1 = &sB[1][(wn * 64 + l16) * 64];

    f16x8 afr[4][2], bfr[2][2][2];
    f32x4 acc[8][4] = {};

#define LDA(PB, MH) do { \
    _Pragma("unroll") \
    for (int ii_ = 0; ii_ < 4; ii_++) { \
        afr[ii_][0] = *(const f16x8*)(PB + ((MH) * 4 + ii_) * 1024 + go0); \
        afr[ii_][1] = *(const f16x8*)(PB + ((MH) * 4 + ii_) * 1024 + go1); \
    } \
} while (0)

#define LDB(PB, NH) do { \
    _Pragma("unroll") \
    for (int jj_ = 0; jj_ < 2; jj_++) { \
        bfr[NH][jj_][0] = *(const f16x8*)(PB + ((NH) * 2 + jj_) * 1024 + go0); \
        bfr[NH][jj_][1] = *(const f16x8*)(PB + ((NH) * 2 + jj_) * 1024 + go1); \
    } \
} while (0)

#define QMFMA(MH, NH) do { \
    __builtin_amdgcn_s_setprio(1); \
    _Pragma("unroll") \
    for (int ii_ = 0; ii_ < 4; ii_++) \
    _Pragma("unroll") \
    for (int jj_ = 0; jj_ < 2; jj_++) { \
        acc[(MH)*4+ii_][(NH)*2+jj_] = __builtin_amdgcn_mfma_f32_16x16x32_f16(afr[ii_][0], bfr[NH][jj_][0], acc[(MH)*4+ii_][(NH)*2+jj_], 0, 0, 0); \
        acc[(MH)*4+ii_][(NH)*2+jj_] = __builtin_amdgcn_mfma_f32_16x16x32_f16(afr[ii_][1], bfr[NH][jj_][1], acc[(MH)*4+ii_][(NH)*2+jj_], 0, 0, 0); \
    } \
    __builtin_amdgcn_s_setprio(0); \
} while (0)

    STAGE(0, 0);
    STAGE(1, 1);
    VMW8();
    BARX();

#pragma unroll 1
    for (int it = 0; it < 16; it++) {
        int kt2 = 2 * it + 2; if (kt2 > 31) kt2 = 31;
        int kt3 = 2 * it + 3; if (kt3 > 31) kt3 = 31;
        LDA(aB0, 0); LDB(bB0, 0);
        BARX(); LGKM0(); QMFMA(0, 0); BARX();
        LDB(bB0, 1);
        BARX(); LGKM0(); QMFMA(0, 1); BARX();
        LDA(aB0, 1);
        BARX(); LGKM0(); QMFMA(1, 0); BARX();
        STAGE(0, kt2);
        VMW8();
        BARX(); QMFMA(1, 1); BARX();
        LDA(aB1, 0); LDB(bB1, 0);
        BARX(); LGKM0(); QMFMA(0, 0); BARX();
        LDB(bB1, 1);
        BARX(); LGKM0(); QMFMA(0, 1); BARX();
        LDA(aB1, 1);
        BARX(); LGKM0(); QMFMA(1, 0); BARX();
        STAGE(1, kt3);
        VMW8();
        BARX(); QMFMA(1, 1); BARX();
    }
    asm volatile("s_waitcnt vmcnt(0)" ::: "memory");

    long rb = (long)bm * 256 + wm * 128 + quad * 4;
    f16* dst; long cw, cb; float sc = 1.f;
    if (bn < 4)      { dst = h0; cw = 1024; cb = (long)bn * 256;       sc = 0.125f; }
    else if (bn < 8) { dst = h1; cw = 1024; cb = (long)(bn - 4) * 256; }
    else             { dst = h2; cw = 2048; cb = (long)(bn - 8) * 256; }
    long cbase = cb + wn * 64 + l16;
#pragma unroll
    for (int i = 0; i < 8; i++)
#pragma unroll
        for (int j = 0; j < 4; j++)
#pragma unroll
            for (int r = 0; r < 4; r++) {
                float x = acc[i][j][r];
                x = x / (1.f + __expf(-x)) * sc;
                dst[(rb + i * 16 + r) * cw + cbase + j * 16] = (f16)x;
            }
#undef STAGE
#undef LDA
#undef LDB
#undef QMFMA
}

// ---------------- 128x256 f16 GEMM (out): full-chip fill at N=2048 ----------------
__global__ __launch_bounds__(512, 2) void gemm128o(const f16* __restrict__ A,
                                                   const f16* __restrict__ Bt,
                                                   float* __restrict__ o0) {
    __shared__ __align__(16) f16 sAb[16384];   // 2 bufs x [128][64] swizzled
    __shared__ __align__(16) f16 sBb[32768];   // 2 bufs x [256][64] swizzled
    int tid = threadIdx.x;
    int wave = tid >> 6, lane = tid & 63;
    int quad = lane >> 4, l16 = lane & 15;
    int wm = wave >> 2, wn = wave & 3;         // 2M x 4N

    int cpx = (int)gridDim.x >> 3;
    int wid = ((int)blockIdx.x & 7) * cpx + ((int)blockIdx.x >> 3);
    int bm = wid & 31, bn = wid >> 5;

    int srow = tid >> 3;
    int gsrc = ((tid & 7) ^ (srow & 7)) * 8;
    const f16* Asrc = A  + ((long)bm * 128 + srow) * 2048 + gsrc;
    const f16* Bsrc = Bt + ((long)bn * 256 + srow) * 2048 + gsrc;

#define STAGE(P, KT) do { \
    _Pragma("unroll") \
    for (int q_ = 0; q_ < 2; q_++) \
        gl_lds16(Asrc + (KT) * 64 + (long)q_ * 64 * 2048, sAb + (P) * 8192 + tid * 8 + q_ * 4096); \
    _Pragma("unroll") \
    for (int q_ = 0; q_ < 4; q_++) \
        gl_lds16(Bsrc + (KT) * 64 + (long)q_ * 64 * 2048, sBb + (P) * 16384 + tid * 8 + q_ * 4096); \
} while (0)

    int go0 = (quad ^ (l16 & 7)) * 8;
    int go1 = go0 ^ 32;
    const f16* pA0 = sAb + (wm * 64 + l16) * 64 + go0;
    const f16* pA1 = sAb + (wm * 64 + l16) * 64 + go1;
    const f16* pB0 = sBb + (wn * 64 + l16) * 64 + go0;
    const f16* pB1 = sBb + (wn * 64 + l16) * 64 + go1;

    f16x8 aX[4], bX[4], aY[4], bY[4];
    f32x4 acc[4][4] = {};

#define RDA(D, PTR, POFF) do { \
    D[0] = *(const f16x8*)((PTR) + (POFF)); \
    D[1] = *(const f16x8*)((PTR) + (POFF) + 1024); \
    D[2] = *(const f16x8*)((PTR) + (POFF) + 2048); \
    D[3] = *(const f16x8*)((PTR) + (POFF) + 3072); \
} while (0)

#define MM(AS, BS) do { \
    __builtin_amdgcn_s_setprio(1); \
    _Pragma("unroll") \
    for (int m_ = 0; m_ < 4; m_++) \
    _Pragma("unroll") \
    for (int n_ = 0; n_ < 4; n_++) \
        acc[m_][n_] = __builtin_amdgcn_mfma_f32_16x16x32_f16(AS[m_], BS[n_], acc[m_][n_], 0, 0, 0); \
    __builtin_amdgcn_s_setprio(0); \
} while (0)

    STAGE(0, 0);
    STAGE(1, 1);
    VMW6();
    BARX();
    RDA(aX, pA0, 0); RDA(bX, pB0, 0);

#pragma unroll 1
    for (int it = 0; it < 16; it++) {
        int c2 = 2 * it + 2; if (c2 > 31) c2 = 31;
        int c3 = 2 * it + 3; if (c3 > 31) c3 = 31;
        RDA(aY, pA1, 0); RDA(bY, pB1, 0);
        MM(aX, bX);
        LGKM0();
        BARX();
        STAGE(0, c2);
        VMW6();
        BARX();
        RDA(aX, pA0, 8192); RDA(bX, pB0, 16384);
        MM(aY, bY);
        RDA(aY, pA1, 8192); RDA(bY, pB1, 16384);
        MM(aX, bX);
        LGKM0();
        BARX();
        STAGE(1, c3);
        VMW6();
        BARX();
        RDA(aX, pA0, 0); RDA(bX, pB0, 0);
        MM(aY, bY);
    }
    asm volatile("s_waitcnt vmcnt(0)" ::: "memory");

    long rb = (long)bm * 128 + wm * 64 + quad * 4;
    long cbase = (long)bn * 256 + wn * 64 + l16;
#pragma unroll
    for (int m = 0; m < 4; m++)
#pragma unroll
        for (int n = 0; n < 4; n++)
#pragma unroll
            for (int r = 0; r < 4; r++)
                o0[(rb + m * 16 + r) * 2048 + cbase + n * 16] = acc[m][n][r];
#undef STAGE
#undef RDA
#undef MM
}

// ---------------- vtrans: v [4096][2048] f16 -> vT [2048][4096] f16 ----------------
__global__ __launch_bounds__(256) void vtrans(const u16* __restrict__ v,
                                              u16* __restrict__ vT) {
    __shared__ uint32_t su[128 * 65];
    int tid = threadIdx.x;
    int t0 = (blockIdx.x >> 5) * 128;
    int e0 = (blockIdx.x & 31) * 64;
#pragma unroll
    for (int i = 0; i < 4; i++) {
        int tr = i * 32 + (tid >> 3);
        int ec = (tid & 7) * 8;
        u16x8 g = *(const u16x8*)(v + (long)(t0 + tr) * 2048 + e0 + ec);
#pragma unroll
        for (int j = 0; j < 8; j++) su[tr * 65 + ec + j] = g[j];
    }
    __syncthreads();
#pragma unroll
    for (int i = 0; i < 2; i++) {
        int er = i * 32 + (tid >> 3);
        int tch = (tid & 7) * 16;
        u16x8 o0, o1;
#pragma unroll
        for (int j = 0; j < 8; j++) {
            o0[j] = (u16)su[(tch + j) * 65 + er];
            o1[j] = (u16)su[(tch + 8 + j) * 65 + er];
        }
        u16* dst = vT + (long)(e0 + er) * 4096 + t0 + tch;
        *(u16x8*)dst = o0;
        *(u16x8*)(dst + 8) = o1;
    }
}

// ---------------- gk_cum ----------------
__global__ __launch_bounds__(256) void gk_cum(const float* __restrict__ t_gk,
                                              const float* __restrict__ Wgk2,
                                              const float* __restrict__ bgk2,
                                              float* __restrict__ G,
                                              float* __restrict__ dec) {
    __shared__ float sT[1024];
    __shared__ float sW[1024];
    __shared__ float sb[64];
    __shared__ float sG[64 * 64];
    int blk = blockIdx.x;
    int c = blk & 31, h = (blk >> 5) & 15, b = blk >> 9;
    int tid = threadIdx.x;
    long rowbase = (long)b * Tq + c * 64;
    {
        int idx = tid * 4;
        *(float4*)&sT[idx] = *(const float4*)(t_gk + rowbase * 16 + idx);
        int rr = idx >> 6, dd = idx & 63;
        *(float4*)&sW[idx] = *(const float4*)(Wgk2 + rr * 1024 + h * 64 + dd);
    }
    if (tid < 64) sb[tid] = bgk2[h * 64 + tid];
    __syncthreads();
    int tquad = tid >> 4, dgrp = tid & 15;
    float4 bg4 = *(float4*)&sb[dgrp * 4];
#pragma unroll
    for (int j = 0; j < 4; j++) {
        int t = tquad * 4 + j;
        float4 z = bg4;
#pragma unroll
        for (int rr = 0; rr < 16; rr++) {
            float tv = sT[t * 16 + rr];
            float4 wv = *(float4*)&sW[rr * 64 + dgrp * 4];
            z.x += tv * wv.x; z.y += tv * wv.y; z.z += tv * wv.z; z.w += tv * wv.w;
        }
        float4 o;
        o.x = (fminf(z.x, 0.f) - log1pf(__expf(-fabsf(z.x)))) * 0.0625f;
        o.y = (fminf(z.y, 0.f) - log1pf(__expf(-fabsf(z.y)))) * 0.0625f;
        o.z = (fminf(z.z, 0.f) - log1pf(__expf(-fabsf(z.z)))) * 0.0625f;
        o.w = (fminf(z.w, 0.f) - log1pf(__expf(-fabsf(z.w)))) * 0.0625f;
        *(float4*)&sG[t * 64 + dgrp * 4] = o;
    }
    __syncthreads();
    if (tid < 64) {
        float run = 0.f;
        for (int t = 0; t < 64; t++) { run += sG[t * 64 + tid]; sG[t * 64 + tid] = run; }
        dec[blk * 64 + tid] = __expf(run);
    }
    __syncthreads();
    float* Gb = G + (long)blk * 4096;
#pragma unroll
    for (int i = 0; i < 4; i++) {
        int f = tid + i * 256;
        *(float4*)(Gb + f * 4) = *(float4*)&sG[f * 4];
    }
}

// ---------------- GLA pass 1 (MFMA): U^T = vT @ k_dec ----------------
// U^T[e][d] = sum_t vT[e][t] * k_dec[t][d]; A = sVT rows (e), B = sKd rows (d, k_dec^T).
// Reuses pass3's proven staging (sVT identical) and GRD fragment reads.
#define GRD(row, kslot) (((row) << 6) + ((((kslot) ^ ((row) & 7))) << 3))
__global__ __launch_bounds__(256) void gla_pass1(const f16* __restrict__ kb,
                                                 const f16* __restrict__ vT,
                                                 const float* __restrict__ G,
                                                 float* __restrict__ U) {
    __shared__ __align__(16) f16 sKd[4096];   // [d 64][t 64] swz (k_dec^T)
    __shared__ __align__(16) f16 sVT[8192];   // [e 128][t 64] swz
    int blk = blockIdx.x;
    int c = blk & 31, h = (blk >> 5) & 15, b = blk >> 9;
    int tid = threadIdx.x;
    long rowbase = (long)b * Tq + c * 64;

    // stage vT tile (linear LDS dest, inverse-swizzled global source)
#pragma unroll
    for (int i = 0; i < 4; i++) {
        int s = tid + i * 256;
        int e = s >> 3, gp = s & 7;
        int gl = gp ^ (e & 7);
        gl_lds16(vT + (long)(h * 128 + e) * 4096 + rowbase + gl * 8, sVT + s * 8);
    }
    // k_dec = k * exp(G_last - G), written TRANSPOSED into sKd (f16, values <= |k|)
#pragma unroll
    for (int i = 0; i < 4; i++) {
        int f = tid + i * 256;
        int t = f >> 4, gi = f & 15;
        int d0 = gi * 4;
        float4 G4 = *(const float4*)(G + (long)blk * 4096 + f * 4);
        float4 GL = *(const float4*)(G + (long)blk * 4096 + 63 * 64 + d0);
        f16x4 k4 = *(const f16x4*)(kb + (rowbase + t) * 1024 + h * 64 + d0);
        float kv[4];
        kv[0] = (float)k4[0] * __expf(GL.x - G4.x);
        kv[1] = (float)k4[1] * __expf(GL.y - G4.y);
        kv[2] = (float)k4[2] * __expf(GL.z - G4.z);
        kv[3] = (float)k4[3] * __expf(GL.w - G4.w);
#pragma unroll
        for (int j = 0; j < 4; j++) {
            int d = d0 + j;
            sKd[(d << 6) + ((((t >> 3) ^ (d & 7))) << 3) + (t & 7)] = (f16)kv[j];
        }
    }
    __syncthreads();   // drains gl_lds16 + ds_writes

    int wv = tid >> 6, lane = tid & 63;
    int quad = lane >> 4, l16 = lane & 15;

    // B fragments (k_dec^T rows d), hoisted
    f16x8 bk[4][2];
#pragma unroll
    for (int dt = 0; dt < 4; dt++) {
        int d = dt * 16 + l16;
        bk[dt][0] = *(const f16x8*)(sKd + GRD(d, quad));
        bk[dt][1] = *(const f16x8*)(sKd + GRD(d, 4 + quad));
    }
    float* Ub = U + (long)blk * 8192;
#pragma unroll
    for (int es = 0; es < 2; es++) {
        int e = wv * 32 + es * 16 + l16;
        f16x8 av0 = *(const f16x8*)(sVT + GRD(e, quad));
        f16x8 av1 = *(const f16x8*)(sVT + GRD(e, 4 + quad));
        int erow = wv * 32 + es * 16 + quad * 4;
#pragma unroll
        for (int dt = 0; dt < 4; dt++) {
            f32x4 cc = {};
            cc = __builtin_amdgcn_mfma_f32_16x16x32_f16(av0, bk[dt][0], cc, 0, 0, 0);
            cc = __builtin_amdgcn_mfma_f32_16x16x32_f16(av1, bk[dt][1], cc, 0, 0, 0);
#pragma unroll
            for (int r = 0; r < 4; r++)
                Ub[(erow + r) * 64 + dt * 16 + l16] = cc[r];
        }
    }
}

// ---------------- GLA pass 2: scan; full-fill 256 blocks, float4 lanes ----------------
__global__ __launch_bounds__(256) void gla_pass2(const float* __restrict__ U,
                                                 const float* __restrict__ dec,
                                                 f16* __restrict__ ShT) {
    int bh = blockIdx.x >> 3;
    int tid = threadIdx.x;
    int e = (blockIdx.x & 7) * 16 + (tid >> 4);
    int d0 = (tid & 15) * 4;
    float4 Sa = {0.f, 0.f, 0.f, 0.f};
    for (int c = 0; c < NCq; c++) {
        long base = ((long)(bh * 32 + c) * 128 + e) * 64 + d0;
        float4 u0 = *(const float4*)(U + base);
        float4 dc0 = *(const float4*)(dec + (bh * 32 + c) * 64 + d0);
        f16x4 sh;
        sh[0] = (f16)Sa.x; sh[1] = (f16)Sa.y; sh[2] = (f16)Sa.z; sh[3] = (f16)Sa.w;
        *(f16x4*)(ShT + base) = sh;
        Sa.x = Sa.x * dc0.x + u0.x; Sa.y = Sa.y * dc0.y + u0.y;
        Sa.z = Sa.z * dc0.z + u0.z; Sa.w = Sa.w * dc0.w + u0.w;
    }
}

// ---------------- GLA pass 3 (MFMA) ----------------
__global__ __launch_bounds__(256) void gla_pass3(const f16* __restrict__ qb,
                                                 const f16* __restrict__ kb,
                                                 const float* __restrict__ G,
                                                 const float* __restrict__ t_g,
                                                 const float* __restrict__ Wg2,
                                                 const float* __restrict__ bg2,
                                                 const float* __restrict__ gnw,
                                                 const f16* __restrict__ ShT,
                                                 const f16* __restrict__ vT,
                                                 f16* __restrict__ Oh) {
    __shared__ __align__(16) f16 sQg[4096];   // [t 64][d 64] swz
    __shared__ __align__(16) f16 sKg[4096];   // [t' 64][d 64] swz
    __shared__ __align__(16) f16 sAh[4096];   // [t 64][t' 64] swz
    __shared__ __align__(16) f16 sST[8192];   // [e 128][d 64] swz
    __shared__ __align__(16) f16 sVT[8192];   // [e 128][t' 64] swz
    __shared__ float sWg[16 * 128];
    __shared__ float sbg[128];
    int blk = blockIdx.x;
    int c = blk & 31, h = (blk >> 5) & 15, b = blk >> 9;
    int tid = threadIdx.x;
    long rowbase = (long)b * Tq + c * 64;

#pragma unroll
    for (int i = 0; i < 4; i++) {
        int s = tid + i * 256;
        int e = s >> 3, gp = s & 7;
        int gl = gp ^ (e & 7);
        gl_lds16(ShT + (long)blk * 8192 + e * 64 + gl * 8, sST + s * 8);
        gl_lds16(vT + (long)(h * 128 + e) * 4096 + rowbase + gl * 8, sVT + s * 8);
    }
#pragma unroll
    for (int i = 0; i < 2; i++) {
        int idx = tid * 4 + i * 1024;
        int rr = idx >> 7, ee = idx & 127;
        *(float4*)&sWg[idx] = *(const float4*)(Wg2 + (long)rr * 2048 + h * 128 + ee);
    }
    if (tid < 128) sbg[tid] = bg2[h * 128 + tid];
#pragma unroll
    for (int i = 0; i < 4; i++) {
        int f = tid + i * 256;
        int t = f >> 4, gi = f & 15;
        float4 G4 = *(const float4*)(G + (long)blk * 4096 + f * 4);
        long gb = (rowbase + t) * 1024 + h * 64 + gi * 4;
        f16x4 q4 = *(const f16x4*)(qb + gb);
        f16x4 k4 = *(const f16x4*)(kb + gb);
        f16x4 qh, kh;
        float ex;
        ex = __expf(G4.x); qh[0] = (f16)((float)q4[0] * ex); kh[0] = (f16)((float)k4[0] / ex);
        ex = __expf(G4.y); qh[1] = (f16)((float)q4[1] * ex); kh[1] = (f16)((float)k4[1] / ex);
        ex = __expf(G4.z); qh[2] = (f16)((float)q4[2] * ex); kh[2] = (f16)((float)k4[2] / ex);
        ex = __expf(G4.w); qh[3] = (f16)((float)q4[3] * ex); kh[3] = (f16)((float)k4[3] / ex);
        int w = (t << 6) + ((((gi >> 1) ^ (t & 7))) << 3) + ((gi & 1) << 2);
        *(f16x4*)(sQg + w) = qh;
        *(f16x4*)(sKg + w) = kh;
    }
    __syncthreads();

    int wv = tid >> 6, lane = tid & 63;
    int quad = lane >> 4, l16 = lane & 15;
    int trow = wv * 16 + l16;

    f16x8 afq[2];
    afq[0] = *(const f16x8*)(sQg + GRD(trow, quad));
    afq[1] = *(const f16x8*)(sQg + GRD(trow, 4 + quad));
#pragma unroll
    for (int j4 = 0; j4 < 4; j4++) {
        int tc = j4 * 16 + l16;
        f16x8 bk0 = *(const f16x8*)(sKg + GRD(tc, quad));
        f16x8 bk1 = *(const f16x8*)(sKg + GRD(tc, 4 + quad));
        f32x4 ca = {};
        ca = __builtin_amdgcn_mfma_f32_16x16x32_f16(afq[0], bk0, ca, 0, 0, 0);
        ca = __builtin_amdgcn_mfma_f32_16x16x32_f16(afq[1], bk1, ca, 0, 0, 0);
#pragma unroll
        for (int r = 0; r < 4; r++) {
            int tr = wv * 16 + quad * 4 + r;
            int tcw = j4 * 16 + l16;
            f16 av = (tcw <= tr) ? (f16)ca[r] : (f16)0.f;
            sAh[(tr << 6) + ((((tcw >> 3) ^ (tr & 7))) << 3) + (tcw & 7)] = av;
        }
    }

    f16x8 afa[2];
    afa[0] = *(const f16x8*)(sAh + GRD(trow, quad));
    afa[1] = *(const f16x8*)(sAh + GRD(trow, 4 + quad));
    f32x4 acc[8];
#pragma unroll
    for (int et = 0; et < 8; et++) {
        int e = et * 16 + l16;
        f16x8 bs0 = *(const f16x8*)(sST + GRD(e, quad));
        f16x8 bs1 = *(const f16x8*)(sST + GRD(e, 4 + quad));
        f16x8 bv0 = *(const f16x8*)(sVT + GRD(e, quad));
        f16x8 bv1 = *(const f16x8*)(sVT + GRD(e, 4 + quad));
        f32x4 cc = {};
        cc = __builtin_amdgcn_mfma_f32_16x16x32_f16(afq[0], bs0, cc, 0, 0, 0);
        cc = __builtin_amdgcn_mfma_f32_16x16x32_f16(afq[1], bs1, cc, 0, 0, 0);
        cc = __builtin_amdgcn_mfma_f32_16x16x32_f16(afa[0], bv0, cc, 0, 0, 0);
        cc = __builtin_amdgcn_mfma_f32_16x16x32_f16(afa[1], bv1, cc, 0, 0, 0);
        acc[et] = cc;
    }

    float gw[8], bgv[8];
#pragma unroll
    for (int et = 0; et < 8; et++) {
        gw[et]  = gnw[et * 16 + l16];
        bgv[et] = sbg[et * 16 + l16];
    }
#pragma unroll
    for (int half = 0; half < 2; half++) {
        float tg[2][16];
#pragma unroll
        for (int rh = 0; rh < 2; rh++) {
            int t = wv * 16 + quad * 4 + half * 2 + rh;
            const float* tgp = t_g + (rowbase + t) * 16;
#pragma unroll
            for (int q4 = 0; q4 < 4; q4++)
                *(float4*)&tg[rh][q4 * 4] = *(const float4*)(tgp + q4 * 4);
        }
        float g[2][8];
#pragma unroll
        for (int rh = 0; rh < 2; rh++)
#pragma unroll
            for (int et = 0; et < 8; et++) g[rh][et] = bgv[et];
#pragma unroll
        for (int rr = 0; rr < 16; rr++) {
#pragma unroll
            for (int et = 0; et < 8; et++) {
                float wv_ = sWg[rr * 128 + et * 16 + l16];
                g[0][et] += tg[0][rr] * wv_;
                g[1][et] += tg[1][rr] * wv_;
            }
        }
#pragma unroll
        for (int rh = 0; rh < 2; rh++) {
            int r = half * 2 + rh;
            int t = wv * 16 + quad * 4 + r;
            float ss = 0.f;
#pragma unroll
            for (int et = 0; et < 8; et++) ss += acc[et][r] * acc[et][r];
            ss += __shfl_xor(ss, 1);
            ss += __shfl_xor(ss, 2);
            ss += __shfl_xor(ss, 4);
            ss += __shfl_xor(ss, 8);
            float scale = rsqrtf(ss * (1.f / 128.f) + 1e-5f);
            long off = (rowbase + t) * 2048 + h * 128 + l16;
#pragma unroll
            for (int et = 0; et < 8; et++) {
                float y = acc[et][r] * scale * gw[et] / (1.f + __expf(-g[rh][et]));
                Oh[off + et * 16] = (f16)y;
            }
        }
    }
}

extern "C" void kernel_launch(void* const* d_in, const int* in_sizes, int n_in,
                              void* d_out, int out_size, void* d_ws, size_t ws_size,
                              hipStream_t stream) {
    const float* hs   = (const float*)d_in[0];
    const float* Wq   = (const float*)d_in[1];
    const float* Wk   = (const float*)d_in[2];
    const float* Wv   = (const float*)d_in[3];
    const float* Wgk1 = (const float*)d_in[4];
    const float* Wgk2 = (const float*)d_in[5];
    const float* bgk2 = (const float*)d_in[6];
    const float* Wg1  = (const float*)d_in[7];
    const float* Wg2  = (const float*)d_in[8];
    const float* bg2  = (const float*)d_in[9];
    const float* Wo   = (const float*)d_in[10];
    const float* gnw  = (const float*)d_in[11];

    char* w = (char*)d_ws;
    auto alloc = [&](size_t bytes) {
        char* p = w; w += (bytes + 255) & ~size_t(255); return (void*)p;
    };
    f16*   Xh     = (f16*)  alloc((size_t)Mq * Dq * 2);        // 16 MB (reused for O)
    f16*   WqkvT  = (f16*)  alloc((size_t)4224 * 2048 * 2);    // 17.3 MB [q|k|v]
    f16*   WoT    = (f16*)  alloc((size_t)2048 * 2048 * 2);    // 8 MB
    f16*   qb     = (f16*)  alloc((size_t)Mq * 1024 * 2);      // 8 MB (f16)
    f16*   kb     = (f16*)  alloc((size_t)Mq * 1024 * 2);      // 8 MB (f16)
    f16*   vhb    = (f16*)  alloc((size_t)Mq * 2048 * 2);      // 16 MB (v row-major)
    f16*   vTb    = (f16*)  alloc((size_t)Mq * 2048 * 2);      // 16 MB (v^T)
    float* t_gk   = (float*)alloc((size_t)Mq * 16 * 4);
    float* t_g    = (float*)alloc((size_t)Mq * 16 * 4);
    float* Ut     = (float*)alloc((size_t)NBH * NCq * 8192 * 4); // 33.5 MB (U^T)
    f16*   ShT    = (f16*)  alloc((size_t)NBH * NCq * 8192 * 2); // 16.8 MB (S^T f16)
    float* dec    = (float*)alloc((size_t)NBH * NCq * 64 * 4);
    float* Gbuf   = (float*)alloc((size_t)NBH * NCq * 4096 * 4); // 16.8 MB

    trans_all<<<3072, 256, 0, stream>>>(Wq, Wk, Wv, Wo, WqkvT, WoT);
    hs_conv<<<Mq * Dq / 2048, 256, 0, stream>>>(hs, Xh);
    lowrank_tg<<<256, 256, 0, stream>>>(hs, Wgk1, Wg1, t_gk, t_g);

    // fused q|k|v GEMM: 256x256 tiles, 16x16 = 256 blocks (exact CU fill)
    gemm256q<<<256, 512, 0, stream>>>(Xh, WqkvT, qb, kb, vhb);
    vtrans<<<1024, 256, 0, stream>>>((const u16*)vhb, (u16*)vTb);

    gk_cum<<<NBH * NCq, 256, 0, stream>>>(t_gk, Wgk2, bgk2, Gbuf, dec);
    gla_pass1<<<NBH * NCq, 256, 0, stream>>>(kb, vTb, Gbuf, Ut);
    gla_pass2<<<NBH * 8, 256, 0, stream>>>(Ut, dec, ShT);
    gla_pass3<<<NBH * NCq, 256, 0, stream>>>(qb, kb, Gbuf, t_g, Wg2, bg2, gnw, ShT, vTb, Xh);

    // out GEMM: 128x256 tiles, 32x8 = 256 blocks (exact CU fill)
    gemm128o<<<256, 512, 0, stream>>>(Xh, WoT, (float*)d_out);
}

// Round 10
// 363.854 us; speedup vs baseline: 1.1521x; 1.1205x over previous
//
#include <hip/hip_runtime.h>
#include <cstdint>

// Problem constants
#define Bq   2
#define Tq   2048
#define Dq   2048
#define Hq   16
#define DKq  64
#define DVq  128
#define Cq   64          // chunk len
#define NCq  32          // chunks
#define Mq   4096        // B*T
#define NBH  32          // B*H

typedef _Float16 f16;
typedef f16 f16x4 __attribute__((ext_vector_type(4)));
typedef f16 f16x8 __attribute__((ext_vector_type(8)));
typedef float f32x4 __attribute__((ext_vector_type(4)));
typedef unsigned short u16;
typedef u16 u16x8 __attribute__((ext_vector_type(8)));

__device__ __forceinline__ void gl_lds16(const void* g, void* l) {
    __builtin_amdgcn_global_load_lds(
        (const __attribute__((address_space(1))) uint32_t*)g,
        (__attribute__((address_space(3))) uint32_t*)l, 16, 0, 0);
}

#define BARX()   asm volatile("s_barrier" ::: "memory")
#define LGKM0()  asm volatile("s_waitcnt lgkmcnt(0)" ::: "memory")
#define VMW8()   asm volatile("s_waitcnt vmcnt(8)" ::: "memory")
#define VMW6()   asm volatile("s_waitcnt vmcnt(6)" ::: "memory")

// ---------------- merged weight transpose to f16 (64x64 tiles, 3072 blocks) ----------------
__global__ __launch_bounds__(256) void trans_all(const float* __restrict__ Wq,
                                                 const float* __restrict__ Wk,
                                                 const float* __restrict__ Wv,
                                                 const float* __restrict__ Wo,
                                                 f16* __restrict__ Qkv, f16* __restrict__ WoT) {
    __shared__ float sh[64 * 65];   // [n 64][k 65] (pad breaks pow-2 stride)
    int blk = blockIdx.x;
    int tid = threadIdx.x;
    const float* W; f16* Dh; int N, nt, kt; long rowoff;
    if (blk < 512)       { W = Wq; N = 1024; int t = blk;        nt = t & 15; kt = t >> 4; Dh = Qkv; rowoff = 0; }
    else if (blk < 1024) { W = Wk; N = 1024; int t = blk - 512;  nt = t & 15; kt = t >> 4; Dh = Qkv; rowoff = 1024; }
    else if (blk < 2048) { W = Wv; N = 2048; int t = blk - 1024; nt = t & 31; kt = t >> 5; Dh = Qkv; rowoff = 2048; }
    else                 { W = Wo; N = 2048; int t = blk - 2048; nt = t & 31; kt = t >> 5; Dh = WoT; rowoff = 0; }
    int k0 = kt * 64, n0 = nt * 64;
    int kr = tid >> 4, nc = (tid & 15) * 4;
#pragma unroll
    for (int p = 0; p < 4; p++) {
        int k = kr + p * 16;
        float4 w4 = *(const float4*)(W + (long)(k0 + k) * N + n0 + nc);
        sh[(nc + 0) * 65 + k] = w4.x;
        sh[(nc + 1) * 65 + k] = w4.y;
        sh[(nc + 2) * 65 + k] = w4.z;
        sh[(nc + 3) * 65 + k] = w4.w;
    }
    __syncthreads();
    int nr = tid >> 3, kch = (tid & 7) * 8;
#pragma unroll
    for (int p = 0; p < 2; p++) {
        int n = nr + p * 32;
        f16x8 o;
#pragma unroll
        for (int j = 0; j < 8; j++) o[j] = (f16)sh[n * 65 + kch + j];
        *(f16x8*)(Dh + (rowoff + n0 + n) * 2048L + k0 + kch) = o;
    }
}

// ---------------- pure f32 -> f16 convert ----------------
__global__ __launch_bounds__(256) void hs_conv(const float* __restrict__ in,
                                               f16* __restrict__ out) {
    long i = ((long)blockIdx.x * 256 + threadIdx.x) * 8;
    float4 a = *(const float4*)(in + i);
    float4 b = *(const float4*)(in + i + 4);
    f16x8 h;
    h[0] = (f16)a.x; h[1] = (f16)a.y; h[2] = (f16)a.z; h[3] = (f16)a.w;
    h[4] = (f16)b.x; h[5] = (f16)b.y; h[6] = (f16)b.z; h[7] = (f16)b.w;
    *(f16x8*)(out + i) = h;
}

// ---------------- low-rank t_gk / t_g ----------------
__global__ __launch_bounds__(256) void lowrank_tg(const float* __restrict__ hs,
                                                  const float* __restrict__ Wgk1,
                                                  const float* __restrict__ Wg1,
                                                  float* __restrict__ t_gk,
                                                  float* __restrict__ t_g) {
    __shared__ float sW[512 * 32];       // 64 KB, granule-swizzled
    int tid = threadIdx.x;
    int blk = blockIdx.x;
    int r = tid >> 4, seg = tid & 15;
    long row = (long)blk * 16 + r;
    float acc[32];
#pragma unroll
    for (int c = 0; c < 32; c++) acc[c] = 0.f;
    for (int kc = 0; kc < 2048; kc += 512) {
        __syncthreads();
#pragma unroll
        for (int i = 0; i < 16; i++) {
            int s = tid + i * 256;
            int k = s >> 3, q = s & 7;
            float4 w = (q < 4) ? *(const float4*)(Wgk1 + (long)(kc + k) * 16 + q * 4)
                               : *(const float4*)(Wg1  + (long)(kc + k) * 16 + (q - 4) * 4);
            int qs = q ^ ((k >> 5) & 7);
            *(float4*)&sW[k * 32 + qs * 4] = w;
        }
        __syncthreads();
        const float* hp = hs + row * 2048 + kc + seg * 32;
        int xr = seg & 7;
#pragma unroll
        for (int k4 = 0; k4 < 8; k4++) {
            float4 hv = *(const float4*)(hp + k4 * 4);
            float hvv[4] = {hv.x, hv.y, hv.z, hv.w};
#pragma unroll
            for (int u = 0; u < 4; u++) {
                int k = seg * 32 + k4 * 4 + u;
                const float* wr = &sW[k * 32];
#pragma unroll
                for (int q = 0; q < 8; q++) {
                    float4 wv = *(const float4*)(wr + ((q ^ xr) * 4));
                    acc[q * 4 + 0] += hvv[u] * wv.x;
                    acc[q * 4 + 1] += hvv[u] * wv.y;
                    acc[q * 4 + 2] += hvv[u] * wv.z;
                    acc[q * 4 + 3] += hvv[u] * wv.w;
                }
            }
        }
    }
#pragma unroll
    for (int c = 0; c < 32; c++) {
        acc[c] += __shfl_xor(acc[c], 1);
        acc[c] += __shfl_xor(acc[c], 2);
        acc[c] += __shfl_xor(acc[c], 4);
        acc[c] += __shfl_xor(acc[c], 8);
    }
    if (seg == 0) {
        float4 a;
        a.x = acc[0];  a.y = acc[1];  a.z = acc[2];  a.w = acc[3];  *(float4*)(t_gk + row * 16)     = a;
        a.x = acc[4];  a.y = acc[5];  a.z = acc[6];  a.w = acc[7];  *(float4*)(t_gk + row * 16 + 4) = a;
        a.x = acc[8];  a.y = acc[9];  a.z = acc[10]; a.w = acc[11]; *(float4*)(t_gk + row * 16 + 8) = a;
        a.x = acc[12]; a.y = acc[13]; a.z = acc[14]; a.w = acc[15]; *(float4*)(t_gk + row * 16 + 12)= a;
        a.x = acc[16]; a.y = acc[17]; a.z = acc[18]; a.w = acc[19]; *(float4*)(t_g + row * 16)      = a;
        a.x = acc[20]; a.y = acc[21]; a.z = acc[22]; a.w = acc[23]; *(float4*)(t_g + row * 16 + 4)  = a;
        a.x = acc[24]; a.y = acc[25]; a.z = acc[26]; a.w = acc[27]; *(float4*)(t_g + row * 16 + 8)  = a;
        a.x = acc[28]; a.y = acc[29]; a.z = acc[30]; a.w = acc[31]; *(float4*)(t_g + row * 16 + 12) = a;
    }
}

// ---------------- 256x256 8-phase f16 GEMM (qkv) ----------------
// q: bn<4 -> h0 (silu*0.125, cw1024); k: bn<8 -> h1 (silu, cw1024);
// v: bn>=8 -> vT DIRECTLY TRANSPOSED (silu, f16 scatter; L2 merges, vT read back soon).
__global__ __launch_bounds__(512, 2) void gemm256q(const f16* __restrict__ A,
                                                   const f16* __restrict__ Bt,
                                                   f16* __restrict__ h0,
                                                   f16* __restrict__ h1,
                                                   f16* __restrict__ vT) {
    __shared__ __align__(16) f16 sA[2][16384];
    __shared__ __align__(16) f16 sB[2][16384];
    int tid = threadIdx.x;
    int wave = tid >> 6, lane = tid & 63;
    int quad = lane >> 4, l16 = lane & 15;
    int wm = wave >> 2, wn = wave & 3;

    int cpx = (int)gridDim.x >> 3;
    int wid = ((int)blockIdx.x & 7) * cpx + ((int)blockIdx.x >> 3);
    int bm = wid & 15, bn = wid >> 4;

    const f16* Ab = A  + (long)bm * 256 * 2048;
    const f16* Bb = Bt + (long)bn * 256 * 2048;

    int srow = tid >> 3;
    int gsrc = ((tid & 7) ^ (srow & 7)) * 8;
    const f16* Asrc = Ab + (long)srow * 2048 + gsrc;
    const f16* Bsrc = Bb + (long)srow * 2048 + gsrc;

#define STAGE(P, KT) do { \
    const f16* as_ = Asrc + (KT) * 64; \
    const f16* bs_ = Bsrc + (KT) * 64; \
    f16* la_ = &sA[P][tid * 8]; \
    f16* lb_ = &sB[P][tid * 8]; \
    _Pragma("unroll") \
    for (int q_ = 0; q_ < 4; q_++) gl_lds16(as_ + (long)q_ * 64 * 2048, la_ + q_ * 4096); \
    _Pragma("unroll") \
    for (int q_ = 0; q_ < 4; q_++) gl_lds16(bs_ + (long)q_ * 64 * 2048, lb_ + q_ * 4096); \
} while (0)

    int go0 = (quad ^ (l16 & 7)) * 8;
    int go1 = go0 ^ 32;
    const f16* aB0 = &sA[0][(wm * 128 + l16) * 64];
    const f16* aB1 = &sA[1][(wm * 128 + l16) * 64];
    const f16* bB0 = &sB[0][(wn * 64 + l16) * 64];
    const f16* bB1 = &sB[1][(wn * 64 + l16) * 64];

    f16x8 afr[4][2], bfr[2][2][2];
    f32x4 acc[8][4] = {};

#define LDA(PB, MH) do { \
    _Pragma("unroll") \
    for (int ii_ = 0; ii_ < 4; ii_++) { \
        afr[ii_][0] = *(const f16x8*)(PB + ((MH) * 4 + ii_) * 1024 + go0); \
        afr[ii_][1] = *(const f16x8*)(PB + ((MH) * 4 + ii_) * 1024 + go1); \
    } \
} while (0)

#define LDB(PB, NH) do { \
    _Pragma("unroll") \
    for (int jj_ = 0; jj_ < 2; jj_++) { \
        bfr[NH][jj_][0] = *(const f16x8*)(PB + ((NH) * 2 + jj_) * 1024 + go0); \
        bfr[NH][jj_][1] = *(const f16x8*)(PB + ((NH) * 2 + jj_) * 1024 + go1); \
    } \
} while (0)

#define QMFMA(MH, NH) do { \
    __builtin_amdgcn_s_setprio(1); \
    _Pragma("unroll") \
    for (int ii_ = 0; ii_ < 4; ii_++) \
    _Pragma("unroll") \
    for (int jj_ = 0; jj_ < 2; jj_++) { \
        acc[(MH)*4+ii_][(NH)*2+jj_] = __builtin_amdgcn_mfma_f32_16x16x32_f16(afr[ii_][0], bfr[NH][jj_][0], acc[(MH)*4+ii_][(NH)*2+jj_], 0, 0, 0); \
        acc[(MH)*4+ii_][(NH)*2+jj_] = __builtin_amdgcn_mfma_f32_16x16x32_f16(afr[ii_][1], bfr[NH][jj_][1], acc[(MH)*4+ii_][(NH)*2+jj_], 0, 0, 0); \
    } \
    __builtin_amdgcn_s_setprio(0); \
} while (0)

    STAGE(0, 0);
    STAGE(1, 1);
    VMW8();
    BARX();

#pragma unroll 1
    for (int it = 0; it < 16; it++) {
        int kt2 = 2 * it + 2; if (kt2 > 31) kt2 = 31;
        int kt3 = 2 * it + 3; if (kt3 > 31) kt3 = 31;
        LDA(aB0, 0); LDB(bB0, 0);
        BARX(); LGKM0(); QMFMA(0, 0); BARX();
        LDB(bB0, 1);
        BARX(); LGKM0(); QMFMA(0, 1); BARX();
        LDA(aB0, 1);
        BARX(); LGKM0(); QMFMA(1, 0); BARX();
        STAGE(0, kt2);
        VMW8();
        BARX(); QMFMA(1, 1); BARX();
        LDA(aB1, 0); LDB(bB1, 0);
        BARX(); LGKM0(); QMFMA(0, 0); BARX();
        LDB(bB1, 1);
        BARX(); LGKM0(); QMFMA(0, 1); BARX();
        LDA(aB1, 1);
        BARX(); LGKM0(); QMFMA(1, 0); BARX();
        STAGE(1, kt3);
        VMW8();
        BARX(); QMFMA(1, 1); BARX();
    }
    asm volatile("s_waitcnt vmcnt(0)" ::: "memory");

    long rb = (long)bm * 256 + wm * 128 + quad * 4;   // token base for this thread
    if (bn >= 8) {
        // v: transposed store vT[e][t], e = v-col, t = token
        long e0 = (long)(bn - 8) * 256 + wn * 64 + l16;
#pragma unroll
        for (int i = 0; i < 8; i++)
#pragma unroll
            for (int j = 0; j < 4; j++)
#pragma unroll
                for (int r = 0; r < 4; r++) {
                    float x = acc[i][j][r];
                    x = x / (1.f + __expf(-x));
                    vT[(e0 + j * 16) * 4096 + rb + i * 16 + r] = (f16)x;
                }
    } else {
        f16* dst; long cb; float sc = 1.f;
        if (bn < 4) { dst = h0; cb = (long)bn * 256;       sc = 0.125f; }
        else        { dst = h1; cb = (long)(bn - 4) * 256; }
        long cbase = cb + wn * 64 + l16;
#pragma unroll
        for (int i = 0; i < 8; i++)
#pragma unroll
            for (int j = 0; j < 4; j++)
#pragma unroll
                for (int r = 0; r < 4; r++) {
                    float x = acc[i][j][r];
                    x = x / (1.f + __expf(-x)) * sc;
                    dst[(rb + i * 16 + r) * 1024 + cbase + j * 16] = (f16)x;
                }
    }
#undef STAGE
#undef LDA
#undef LDB
#undef QMFMA
}

// ---------------- 128x256 f16 GEMM (out): full-chip fill at N=2048 ----------------
__global__ __launch_bounds__(512, 2) void gemm128o(const f16* __restrict__ A,
                                                   const f16* __restrict__ Bt,
                                                   float* __restrict__ o0) {
    __shared__ __align__(16) f16 sAb[16384];   // 2 bufs x [128][64] swizzled
    __shared__ __align__(16) f16 sBb[32768];   // 2 bufs x [256][64] swizzled
    int tid = threadIdx.x;
    int wave = tid >> 6, lane = tid & 63;
    int quad = lane >> 4, l16 = lane & 15;
    int wm = wave >> 2, wn = wave & 3;         // 2M x 4N

    int cpx = (int)gridDim.x >> 3;
    int wid = ((int)blockIdx.x & 7) * cpx + ((int)blockIdx.x >> 3);
    int bm = wid & 31, bn = wid >> 5;

    int srow = tid >> 3;
    int gsrc = ((tid & 7) ^ (srow & 7)) * 8;
    const f16* Asrc = A  + ((long)bm * 128 + srow) * 2048 + gsrc;
    const f16* Bsrc = Bt + ((long)bn * 256 + srow) * 2048 + gsrc;

#define STAGE(P, KT) do { \
    _Pragma("unroll") \
    for (int q_ = 0; q_ < 2; q_++) \
        gl_lds16(Asrc + (KT) * 64 + (long)q_ * 64 * 2048, sAb + (P) * 8192 + tid * 8 + q_ * 4096); \
    _Pragma("unroll") \
    for (int q_ = 0; q_ < 4; q_++) \
        gl_lds16(Bsrc + (KT) * 64 + (long)q_ * 64 * 2048, sBb + (P) * 16384 + tid * 8 + q_ * 4096); \
} while (0)

    int go0 = (quad ^ (l16 & 7)) * 8;
    int go1 = go0 ^ 32;
    const f16* pA0 = sAb + (wm * 64 + l16) * 64 + go0;
    const f16* pA1 = sAb + (wm * 64 + l16) * 64 + go1;
    const f16* pB0 = sBb + (wn * 64 + l16) * 64 + go0;
    const f16* pB1 = sBb + (wn * 64 + l16) * 64 + go1;

    f16x8 aX[4], bX[4], aY[4], bY[4];
    f32x4 acc[4][4] = {};

#define RDA(D, PTR, POFF) do { \
    D[0] = *(const f16x8*)((PTR) + (POFF)); \
    D[1] = *(const f16x8*)((PTR) + (POFF) + 1024); \
    D[2] = *(const f16x8*)((PTR) + (POFF) + 2048); \
    D[3] = *(const f16x8*)((PTR) + (POFF) + 3072); \
} while (0)

#define MM(AS, BS) do { \
    __builtin_amdgcn_s_setprio(1); \
    _Pragma("unroll") \
    for (int m_ = 0; m_ < 4; m_++) \
    _Pragma("unroll") \
    for (int n_ = 0; n_ < 4; n_++) \
        acc[m_][n_] = __builtin_amdgcn_mfma_f32_16x16x32_f16(AS[m_], BS[n_], acc[m_][n_], 0, 0, 0); \
    __builtin_amdgcn_s_setprio(0); \
} while (0)

    STAGE(0, 0);
    STAGE(1, 1);
    VMW6();
    BARX();
    RDA(aX, pA0, 0); RDA(bX, pB0, 0);

#pragma unroll 1
    for (int it = 0; it < 16; it++) {
        int c2 = 2 * it + 2; if (c2 > 31) c2 = 31;
        int c3 = 2 * it + 3; if (c3 > 31) c3 = 31;
        RDA(aY, pA1, 0); RDA(bY, pB1, 0);
        MM(aX, bX);
        LGKM0();
        BARX();
        STAGE(0, c2);
        VMW6();
        BARX();
        RDA(aX, pA0, 8192); RDA(bX, pB0, 16384);
        MM(aY, bY);
        RDA(aY, pA1, 8192); RDA(bY, pB1, 16384);
        MM(aX, bX);
        LGKM0();
        BARX();
        STAGE(1, c3);
        VMW6();
        BARX();
        RDA(aX, pA0, 0); RDA(bX, pB0, 0);
        MM(aY, bY);
    }
    asm volatile("s_waitcnt vmcnt(0)" ::: "memory");

    long rb = (long)bm * 128 + wm * 64 + quad * 4;
    long cbase = (long)bn * 256 + wn * 64 + l16;
#pragma unroll
    for (int m = 0; m < 4; m++)
#pragma unroll
        for (int n = 0; n < 4; n++)
#pragma unroll
            for (int r = 0; r < 4; r++)
                o0[(rb + m * 16 + r) * 2048 + cbase + n * 16] = acc[m][n][r];
#undef STAGE
#undef RDA
#undef MM
}

// ---------------- gk_cum ----------------
__global__ __launch_bounds__(256) void gk_cum(const float* __restrict__ t_gk,
                                              const float* __restrict__ Wgk2,
                                              const float* __restrict__ bgk2,
                                              float* __restrict__ G,
                                              float* __restrict__ dec) {
    __shared__ float sT[1024];
    __shared__ float sW[1024];
    __shared__ float sb[64];
    __shared__ float sG[64 * 64];
    int blk = blockIdx.x;
    int c = blk & 31, h = (blk >> 5) & 15, b = blk >> 9;
    int tid = threadIdx.x;
    long rowbase = (long)b * Tq + c * 64;
    {
        int idx = tid * 4;
        *(float4*)&sT[idx] = *(const float4*)(t_gk + rowbase * 16 + idx);
        int rr = idx >> 6, dd = idx & 63;
        *(float4*)&sW[idx] = *(const float4*)(Wgk2 + rr * 1024 + h * 64 + dd);
    }
    if (tid < 64) sb[tid] = bgk2[h * 64 + tid];
    __syncthreads();
    int tquad = tid >> 4, dgrp = tid & 15;
    float4 bg4 = *(float4*)&sb[dgrp * 4];
#pragma unroll
    for (int j = 0; j < 4; j++) {
        int t = tquad * 4 + j;
        float4 z = bg4;
#pragma unroll
        for (int rr = 0; rr < 16; rr++) {
            float tv = sT[t * 16 + rr];
            float4 wv = *(float4*)&sW[rr * 64 + dgrp * 4];
            z.x += tv * wv.x; z.y += tv * wv.y; z.z += tv * wv.z; z.w += tv * wv.w;
        }
        float4 o;
        o.x = (fminf(z.x, 0.f) - log1pf(__expf(-fabsf(z.x)))) * 0.0625f;
        o.y = (fminf(z.y, 0.f) - log1pf(__expf(-fabsf(z.y)))) * 0.0625f;
        o.z = (fminf(z.z, 0.f) - log1pf(__expf(-fabsf(z.z)))) * 0.0625f;
        o.w = (fminf(z.w, 0.f) - log1pf(__expf(-fabsf(z.w)))) * 0.0625f;
        *(float4*)&sG[t * 64 + dgrp * 4] = o;
    }
    __syncthreads();
    if (tid < 64) {
        float run = 0.f;
        for (int t = 0; t < 64; t++) { run += sG[t * 64 + tid]; sG[t * 64 + tid] = run; }
        dec[blk * 64 + tid] = __expf(run);
    }
    __syncthreads();
    float* Gb = G + (long)blk * 4096;
#pragma unroll
    for (int i = 0; i < 4; i++) {
        int f = tid + i * 256;
        *(float4*)(Gb + f * 4) = *(float4*)&sG[f * 4];
    }
}

// ---------------- GLA pass 1 (MFMA): U^T = vT @ k_dec, f16 out ----------------
#define GRD(row, kslot) (((row) << 6) + ((((kslot) ^ ((row) & 7))) << 3))
__global__ __launch_bounds__(256) void gla_pass1(const f16* __restrict__ kb,
                                                 const f16* __restrict__ vT,
                                                 const float* __restrict__ G,
                                                 f16* __restrict__ U) {
    __shared__ __align__(16) f16 sKd[4096];   // [d 64][t 64] swz (k_dec^T)
    __shared__ __align__(16) f16 sVT[8192];   // [e 128][t 64] swz
    int blk = blockIdx.x;
    int c = blk & 31, h = (blk >> 5) & 15, b = blk >> 9;
    int tid = threadIdx.x;
    long rowbase = (long)b * Tq + c * 64;

#pragma unroll
    for (int i = 0; i < 4; i++) {
        int s = tid + i * 256;
        int e = s >> 3, gp = s & 7;
        int gl = gp ^ (e & 7);
        gl_lds16(vT + (long)(h * 128 + e) * 4096 + rowbase + gl * 8, sVT + s * 8);
    }
    // k_dec = k * exp(G_last - G), written TRANSPOSED into sKd (f16, values <= |k|)
#pragma unroll
    for (int i = 0; i < 4; i++) {
        int f = tid + i * 256;
        int t = f >> 4, gi = f & 15;
        int d0 = gi * 4;
        float4 G4 = *(const float4*)(G + (long)blk * 4096 + f * 4);
        float4 GL = *(const float4*)(G + (long)blk * 4096 + 63 * 64 + d0);
        f16x4 k4 = *(const f16x4*)(kb + (rowbase + t) * 1024 + h * 64 + d0);
        float kv[4];
        kv[0] = (float)k4[0] * __expf(GL.x - G4.x);
        kv[1] = (float)k4[1] * __expf(GL.y - G4.y);
        kv[2] = (float)k4[2] * __expf(GL.z - G4.z);
        kv[3] = (float)k4[3] * __expf(GL.w - G4.w);
#pragma unroll
        for (int j = 0; j < 4; j++) {
            int d = d0 + j;
            sKd[(d << 6) + ((((t >> 3) ^ (d & 7))) << 3) + (t & 7)] = (f16)kv[j];
        }
    }
    __syncthreads();

    int wv = tid >> 6, lane = tid & 63;
    int quad = lane >> 4, l16 = lane & 15;

    f16x8 bk[4][2];
#pragma unroll
    for (int dt = 0; dt < 4; dt++) {
        int d = dt * 16 + l16;
        bk[dt][0] = *(const f16x8*)(sKd + GRD(d, quad));
        bk[dt][1] = *(const f16x8*)(sKd + GRD(d, 4 + quad));
    }
    f16* Ub = U + (long)blk * 8192;
#pragma unroll
    for (int es = 0; es < 2; es++) {
        int e = wv * 32 + es * 16 + l16;
        f16x8 av0 = *(const f16x8*)(sVT + GRD(e, quad));
        f16x8 av1 = *(const f16x8*)(sVT + GRD(e, 4 + quad));
        int erow = wv * 32 + es * 16 + quad * 4;
#pragma unroll
        for (int dt = 0; dt < 4; dt++) {
            f32x4 cc = {};
            cc = __builtin_amdgcn_mfma_f32_16x16x32_f16(av0, bk[dt][0], cc, 0, 0, 0);
            cc = __builtin_amdgcn_mfma_f32_16x16x32_f16(av1, bk[dt][1], cc, 0, 0, 0);
#pragma unroll
            for (int r = 0; r < 4; r++)
                Ub[(erow + r) * 64 + dt * 16 + l16] = (f16)cc[r];
        }
    }
}

// ---------------- GLA pass 2: scan; U^T f16 in, ShT f16 out ----------------
__global__ __launch_bounds__(256) void gla_pass2(const f16* __restrict__ U,
                                                 const float* __restrict__ dec,
                                                 f16* __restrict__ ShT) {
    int bh = blockIdx.x >> 3;
    int tid = threadIdx.x;
    int e = (blockIdx.x & 7) * 16 + (tid >> 4);
    int d0 = (tid & 15) * 4;
    float4 Sa = {0.f, 0.f, 0.f, 0.f};
    for (int c = 0; c < NCq; c++) {
        long base = ((long)(bh * 32 + c) * 128 + e) * 64 + d0;
        f16x4 u4 = *(const f16x4*)(U + base);
        float4 dc0 = *(const float4*)(dec + (bh * 32 + c) * 64 + d0);
        f16x4 sh;
        sh[0] = (f16)Sa.x; sh[1] = (f16)Sa.y; sh[2] = (f16)Sa.z; sh[3] = (f16)Sa.w;
        *(f16x4*)(ShT + base) = sh;
        Sa.x = Sa.x * dc0.x + (float)u4[0]; Sa.y = Sa.y * dc0.y + (float)u4[1];
        Sa.z = Sa.z * dc0.z + (float)u4[2]; Sa.w = Sa.w * dc0.w + (float)u4[3];
    }
}

// ---------------- GLA pass 3 (MFMA) ----------------
__global__ __launch_bounds__(256) void gla_pass3(const f16* __restrict__ qb,
                                                 const f16* __restrict__ kb,
                                                 const float* __restrict__ G,
                                                 const float* __restrict__ t_g,
                                                 const float* __restrict__ Wg2,
                                                 const float* __restrict__ bg2,
                                                 const float* __restrict__ gnw,
                                                 const f16* __restrict__ ShT,
                                                 const f16* __restrict__ vT,
                                                 f16* __restrict__ Oh) {
    __shared__ __align__(16) f16 sQg[4096];   // [t 64][d 64] swz
    __shared__ __align__(16) f16 sKg[4096];   // [t' 64][d 64] swz
    __shared__ __align__(16) f16 sAh[4096];   // [t 64][t' 64] swz
    __shared__ __align__(16) f16 sST[8192];   // [e 128][d 64] swz
    __shared__ __align__(16) f16 sVT[8192];   // [e 128][t' 64] swz
    __shared__ float sWg[16 * 128];
    __shared__ float sbg[128];
    int blk = blockIdx.x;
    int c = blk & 31, h = (blk >> 5) & 15, b = blk >> 9;
    int tid = threadIdx.x;
    long rowbase = (long)b * Tq + c * 64;

#pragma unroll
    for (int i = 0; i < 4; i++) {
        int s = tid + i * 256;
        int e = s >> 3, gp = s & 7;
        int gl = gp ^ (e & 7);
        gl_lds16(ShT + (long)blk * 8192 + e * 64 + gl * 8, sST + s * 8);
        gl_lds16(vT + (long)(h * 128 + e) * 4096 + rowbase + gl * 8, sVT + s * 8);
    }
#pragma unroll
    for (int i = 0; i < 2; i++) {
        int idx = tid * 4 + i * 1024;
        int rr = idx >> 7, ee = idx & 127;
        *(float4*)&sWg[idx] = *(const float4*)(Wg2 + (long)rr * 2048 + h * 128 + ee);
    }
    if (tid < 128) sbg[tid] = bg2[h * 128 + tid];
#pragma unroll
    for (int i = 0; i < 4; i++) {
        int f = tid + i * 256;
        int t = f >> 4, gi = f & 15;
        float4 G4 = *(const float4*)(G + (long)blk * 4096 + f * 4);
        long gb = (rowbase + t) * 1024 + h * 64 + gi * 4;
        f16x4 q4 = *(const f16x4*)(qb + gb);
        f16x4 k4 = *(const f16x4*)(kb + gb);
        f16x4 qh, kh;
        float ex;
        ex = __expf(G4.x); qh[0] = (f16)((float)q4[0] * ex); kh[0] = (f16)((float)k4[0] / ex);
        ex = __expf(G4.y); qh[1] = (f16)((float)q4[1] * ex); kh[1] = (f16)((float)k4[1] / ex);
        ex = __expf(G4.z); qh[2] = (f16)((float)q4[2] * ex); kh[2] = (f16)((float)k4[2] / ex);
        ex = __expf(G4.w); qh[3] = (f16)((float)q4[3] * ex); kh[3] = (f16)((float)k4[3] / ex);
        int w = (t << 6) + ((((gi >> 1) ^ (t & 7))) << 3) + ((gi & 1) << 2);
        *(f16x4*)(sQg + w) = qh;
        *(f16x4*)(sKg + w) = kh;
    }
    __syncthreads();

    int wv = tid >> 6, lane = tid & 63;
    int quad = lane >> 4, l16 = lane & 15;
    int trow = wv * 16 + l16;

    f16x8 afq[2];
    afq[0] = *(const f16x8*)(sQg + GRD(trow, quad));
    afq[1] = *(const f16x8*)(sQg + GRD(trow, 4 + quad));
#pragma unroll
    for (int j4 = 0; j4 < 4; j4++) {
        int tc = j4 * 16 + l16;
        f16x8 bk0 = *(const f16x8*)(sKg + GRD(tc, quad));
        f16x8 bk1 = *(const f16x8*)(sKg + GRD(tc, 4 + quad));
        f32x4 ca = {};
        ca = __builtin_amdgcn_mfma_f32_16x16x32_f16(afq[0], bk0, ca, 0, 0, 0);
        ca = __builtin_amdgcn_mfma_f32_16x16x32_f16(afq[1], bk1, ca, 0, 0, 0);
#pragma unroll
        for (int r = 0; r < 4; r++) {
            int tr = wv * 16 + quad * 4 + r;
            int tcw = j4 * 16 + l16;
            f16 av = (tcw <= tr) ? (f16)ca[r] : (f16)0.f;
            sAh[(tr << 6) + ((((tcw >> 3) ^ (tr & 7))) << 3) + (tcw & 7)] = av;
        }
    }

    f16x8 afa[2];
    afa[0] = *(const f16x8*)(sAh + GRD(trow, quad));
    afa[1] = *(const f16x8*)(sAh + GRD(trow, 4 + quad));
    f32x4 acc[8];
#pragma unroll
    for (int et = 0; et < 8; et++) {
        int e = et * 16 + l16;
        f16x8 bs0 = *(const f16x8*)(sST + GRD(e, quad));
        f16x8 bs1 = *(const f16x8*)(sST + GRD(e, 4 + quad));
        f16x8 bv0 = *(const f16x8*)(sVT + GRD(e, quad));
        f16x8 bv1 = *(const f16x8*)(sVT + GRD(e, 4 + quad));
        f32x4 cc = {};
        cc = __builtin_amdgcn_mfma_f32_16x16x32_f16(afq[0], bs0, cc, 0, 0, 0);
        cc = __builtin_amdgcn_mfma_f32_16x16x32_f16(afq[1], bs1, cc, 0, 0, 0);
        cc = __builtin_amdgcn_mfma_f32_16x16x32_f16(afa[0], bv0, cc, 0, 0, 0);
        cc = __builtin_amdgcn_mfma_f32_16x16x32_f16(afa[1], bv1, cc, 0, 0, 0);
        acc[et] = cc;
    }

    float gw[8], bgv[8];
#pragma unroll
    for (int et = 0; et < 8; et++) {
        gw[et]  = gnw[et * 16 + l16];
        bgv[et] = sbg[et * 16 + l16];
    }
#pragma unroll
    for (int half = 0; half < 2; half++) {
        float tg[2][16];
#pragma unroll
        for (int rh = 0; rh < 2; rh++) {
            int t = wv * 16 + quad * 4 + half * 2 + rh;
            const float* tgp = t_g + (rowbase + t) * 16;
#pragma unroll
            for (int q4 = 0; q4 < 4; q4++)
                *(float4*)&tg[rh][q4 * 4] = *(const float4*)(tgp + q4 * 4);
        }
        float g[2][8];
#pragma unroll
        for (int rh = 0; rh < 2; rh++)
#pragma unroll
            for (int et = 0; et < 8; et++) g[rh][et] = bgv[et];
#pragma unroll
        for (int rr = 0; rr < 16; rr++) {
#pragma unroll
            for (int et = 0; et < 8; et++) {
                float wv_ = sWg[rr * 128 + et * 16 + l16];
                g[0][et] += tg[0][rr] * wv_;
                g[1][et] += tg[1][rr] * wv_;
            }
        }
#pragma unroll
        for (int rh = 0; rh < 2; rh++) {
            int r = half * 2 + rh;
            int t = wv * 16 + quad * 4 + r;
            float ss = 0.f;
#pragma unroll
            for (int et = 0; et < 8; et++) ss += acc[et][r] * acc[et][r];
            ss += __shfl_xor(ss, 1);
            ss += __shfl_xor(ss, 2);
            ss += __shfl_xor(ss, 4);
            ss += __shfl_xor(ss, 8);
            float scale = rsqrtf(ss * (1.f / 128.f) + 1e-5f);
            long off = (rowbase + t) * 2048 + h * 128 + l16;
#pragma unroll
            for (int et = 0; et < 8; et++) {
                float y = acc[et][r] * scale * gw[et] / (1.f + __expf(-g[rh][et]));
                Oh[off + et * 16] = (f16)y;
            }
        }
    }
}

extern "C" void kernel_launch(void* const* d_in, const int* in_sizes, int n_in,
                              void* d_out, int out_size, void* d_ws, size_t ws_size,
                              hipStream_t stream) {
    const float* hs   = (const float*)d_in[0];
    const float* Wq   = (const float*)d_in[1];
    const float* Wk   = (const float*)d_in[2];
    const float* Wv   = (const float*)d_in[3];
    const float* Wgk1 = (const float*)d_in[4];
    const float* Wgk2 = (const float*)d_in[5];
    const float* bgk2 = (const float*)d_in[6];
    const float* Wg1  = (const float*)d_in[7];
    const float* Wg2  = (const float*)d_in[8];
    const float* bg2  = (const float*)d_in[9];
    const float* Wo   = (const float*)d_in[10];
    const float* gnw  = (const float*)d_in[11];

    char* w = (char*)d_ws;
    auto alloc = [&](size_t bytes) {
        char* p = w; w += (bytes + 255) & ~size_t(255); return (void*)p;
    };
    f16*   Xh     = (f16*)  alloc((size_t)Mq * Dq * 2);        // 16 MB (reused for O)
    f16*   WqkvT  = (f16*)  alloc((size_t)4224 * 2048 * 2);    // 17.3 MB [q|k|v]
    f16*   WoT    = (f16*)  alloc((size_t)2048 * 2048 * 2);    // 8 MB
    f16*   qb     = (f16*)  alloc((size_t)Mq * 1024 * 2);      // 8 MB (f16)
    f16*   kb     = (f16*)  alloc((size_t)Mq * 1024 * 2);      // 8 MB (f16)
    f16*   vTb    = (f16*)  alloc((size_t)Mq * 2048 * 2);      // 16 MB (v^T, written by gemm256q)
    float* t_gk   = (float*)alloc((size_t)Mq * 16 * 4);
    float* t_g    = (float*)alloc((size_t)Mq * 16 * 4);
    f16*   Ut     = (f16*)  alloc((size_t)NBH * NCq * 8192 * 2); // 16.8 MB (U^T f16)
    f16*   ShT    = (f16*)  alloc((size_t)NBH * NCq * 8192 * 2); // 16.8 MB (S^T f16)
    float* dec    = (float*)alloc((size_t)NBH * NCq * 64 * 4);
    float* Gbuf   = (float*)alloc((size_t)NBH * NCq * 4096 * 4); // 16.8 MB

    trans_all<<<3072, 256, 0, stream>>>(Wq, Wk, Wv, Wo, WqkvT, WoT);
    hs_conv<<<Mq * Dq / 2048, 256, 0, stream>>>(hs, Xh);
    lowrank_tg<<<256, 256, 0, stream>>>(hs, Wgk1, Wg1, t_gk, t_g);

    // fused q|k|v GEMM: v written directly transposed (vtrans eliminated)
    gemm256q<<<256, 512, 0, stream>>>(Xh, WqkvT, qb, kb, vTb);

    gk_cum<<<NBH * NCq, 256, 0, stream>>>(t_gk, Wgk2, bgk2, Gbuf, dec);
    gla_pass1<<<NBH * NCq, 256, 0, stream>>>(kb, vTb, Gbuf, Ut);
    gla_pass2<<<NBH * 8, 256, 0, stream>>>(Ut, dec, ShT);
    gla_pass3<<<NBH * NCq, 256, 0, stream>>>(qb, kb, Gbuf, t_g, Wg2, bg2, gnw, ShT, vTb, Xh);

    // out GEMM: 128x256 tiles, 32x8 = 256 blocks (exact CU fill)
    gemm128o<<<256, 512, 0, stream>>>(Xh, WoT, (float*)d_out);
}